// Round 14
// baseline (513.169 us; speedup 1.0000x reference)
//
#include <hip/hip_runtime.h>
#include <math.h>

// ---------------- problem constants ----------------
#define BB 4
#define SS 2048
#define DD 2048
#define HH 16
#define NOPE 128
#define ROPE 64
#define VD 128
#define QKD 192         // NOPE+ROPE
#define KVR 512
#define NP1 3712        // merged proj1 width: 3072 (q) + 640 (kv_a padded)
#define ROWS (BB*SS)    // 8192
// log2(e) / sqrt(192), folded into wq at cast time
#define SCL2 0.1041216338380858f

typedef __attribute__((ext_vector_type(8))) short bf16x8;
typedef __attribute__((ext_vector_type(4))) float f32x4;
typedef unsigned short bfu;
typedef __attribute__((address_space(1))) const void GV;
typedef __attribute__((address_space(3))) void LV;

__device__ __forceinline__ float bf2f(unsigned int u) {
    unsigned int i = u << 16; float f; __builtin_memcpy(&f, &i, 4); return f;
}
__device__ __forceinline__ unsigned int f2bf(float f) {
    unsigned int i; __builtin_memcpy(&i, &f, 4);
    return (i + 0x7fffu + ((i >> 16) & 1u)) >> 16;
}
__device__ __forceinline__ unsigned int cvt_pk_bf16(float lo, float hi) {
    unsigned int r;
    asm("v_cvt_pk_bf16_f32 %0, %1, %2" : "=v"(r) : "v"(lo), "v"(hi));
    return r;
}

// ---------------- one fused cast: x | wq*SCL2 | wkv_a(+pad) | wkv_b(->wkb/wvb) | wo ----------------
__global__ void cast_all(const float* __restrict__ x, const float* __restrict__ wq,
                         const float* __restrict__ wa, const float* __restrict__ wb,
                         const float* __restrict__ wo,
                         bfu* __restrict__ dx, bfu* __restrict__ dq,
                         bfu* __restrict__ da, bfu* __restrict__ dkb,
                         bfu* __restrict__ dvb, bfu* __restrict__ dwo) {
    long i = (long)blockIdx.x * 256 + threadIdx.x;   // one float4 each
    const float* src; bfu* dst; long off, n_src; float scl = 1.0f;
    if (i < 4194304L)        { src = x;  dst = dx;  off = i;            n_src = 4194304L; }
    else if (i < 5767168L)   { src = wq; dst = dq;  off = i - 4194304L; n_src = 1572864L; scl = SCL2; }
    else if (i < 6094848L)   { src = wa; dst = da;  off = i - 5767168L; n_src = 294912L;  }
    else if (i < 6619136L)   {          // wkv_b: split K-rows / V-rows
        long off2 = i - 6094848L;       // float4 index into wkv_b [4096][128]
        long row = off2 >> 7, c = off2 & 127;
        long h = row >> 8, wi = row & 255;
        bfu* d2 = (wi < 128) ? dkb : dvb;
        long drow = (h << 7) + (wi & 127);
        float4 v = ((const float4*)wb)[off2];
        unsigned int lo = f2bf(v.x) | (f2bf(v.y) << 16);
        unsigned int hi = f2bf(v.z) | (f2bf(v.w) << 16);
        ((uint2*)d2)[drow * 128 + c] = make_uint2(lo, hi);
        return;
    }
    else if (i < 7667712L)   { src = wo; dst = dwo; off = i - 6619136L; n_src = 1048576L; }
    else return;
    unsigned int lo = 0, hi = 0;
    if (off < n_src) {
        float4 v = ((const float4*)src)[off];
        lo = f2bf(v.x * scl) | (f2bf(v.y * scl) << 16);
        hi = f2bf(v.z * scl) | (f2bf(v.w * scl) << 16);
    }
    ((uint2*)dst)[off] = make_uint2(lo, hi);
}

// ---------------- 128x128 tile bf16 GEMM, C = A[M,K] @ Bt[N,K]^T ----------------
// MODE 1: f32 out to Cv.
// MODE 2 (kv_b K-part, N=2048): col=h*128+d -> kall (C2).
// MODE 3 (proj1, N=3712): col<3072 -> qr rope-layout (Cv); col>=3072 -> kv1 [row][640] (C2).
// MODE 4 (V^T, M=2048, N=8192): row=h*128+v, col=b*2048+s -> vt[b][h][v][s] (Cv).
// XCD-aware bijective block swizzle (grid size always % 8 == 0 here).
template <int MODE>
__global__ void __launch_bounds__(256)
gemm_bt(const bfu* __restrict__ A, const bfu* __restrict__ Bt,
        void* __restrict__ Cv, bfu* __restrict__ C2, int N, int K) {
    __shared__ __align__(16) char lds[32768];
    char* AsB = lds;
    char* BsB = lds + 16384;
    const int tid  = threadIdx.x;
    const int lane = tid & 63;
    const int wid  = tid >> 6;
    const int wr   = wid >> 1, wc = wid & 1;
    const int nwg  = gridDim.x * gridDim.y;
    const int flat = blockIdx.y * gridDim.x + blockIdx.x;
    const int swz  = (flat & 7) * (nwg >> 3) + (flat >> 3);
    const long m0 = (long)(swz / gridDim.x) * 128;
    const long n0 = (long)(swz % gridDim.x) * 128;

    f32x4 acc[4][4] = {};

    const int lr = lane >> 3;            // row within 8-row stripe
    const int SB = (lane & 7) << 4;      // 16B slot within 128B row

    for (int k0 = 0; k0 < K; k0 += 64) {
        __syncthreads();
#pragma unroll
        for (int i = 0; i < 4; ++i) {
            int rb = wid * 32 + i * 8;   // wave-uniform row base
            int R  = rb + lr;
            int c  = (SB ^ ((R & 7) << 4)) >> 1;   // pre-swizzled source column
            const bfu* gA = A  + (m0 + R) * (long)K + k0 + c;
            const bfu* gB = Bt + (n0 + R) * (long)K + k0 + c;
            __builtin_amdgcn_global_load_lds((GV*)gA, (LV*)(AsB + rb * 128), 16, 0, 0);
            __builtin_amdgcn_global_load_lds((GV*)gB, (LV*)(BsB + rb * 128), 16, 0, 0);
        }
        __syncthreads();
#pragma unroll
        for (int kk = 0; kk < 2; ++kk) {
            bf16x8 av[4], bv[4];
            const int cb = kk * 64 + ((lane >> 4) << 4);
#pragma unroll
            for (int m = 0; m < 4; ++m) {
                int R = wr * 64 + m * 16 + (lane & 15);
                av[m] = *(const bf16x8*)(AsB + R * 128 + (cb ^ ((R & 7) << 4)));
            }
#pragma unroll
            for (int n = 0; n < 4; ++n) {
                int R = wc * 64 + n * 16 + (lane & 15);
                bv[n] = *(const bf16x8*)(BsB + R * 128 + (cb ^ ((R & 7) << 4)));
            }
#pragma unroll
            for (int m = 0; m < 4; ++m)
#pragma unroll
                for (int n = 0; n < 4; ++n)
                    acc[m][n] = __builtin_amdgcn_mfma_f32_16x16x32_bf16(av[m], bv[n], acc[m][n], 0, 0, 0);
        }
    }

    const int cr = (lane >> 4) << 2;
    const int cc = lane & 15;
#pragma unroll
    for (int m = 0; m < 4; ++m)
#pragma unroll
        for (int n = 0; n < 4; ++n)
#pragma unroll
            for (int r = 0; r < 4; ++r) {
                long row = m0 + wr * 64 + m * 16 + cr + r;
                long col = n0 + wc * 64 + n * 16 + cc;
                float val = acc[m][n][r];
                if (MODE == 1) {
                    ((float*)Cv)[row * N + col] = val;
                } else if (MODE == 2) {   // kv_b K-part: col = h*128+d
                    long b_ = row >> 11;
                    long s  = row & 2047;
                    long h  = col >> 7;
                    long d  = col & 127;
                    C2[((b_ * HH + h) * SS + s) * (long)QKD + d] = (bfu)f2bf(val);
                } else if (MODE == 3) {   // proj1 split (N==3712)
                    long b_ = row >> 11;
                    long s  = row & 2047;
                    if (col < 3072) {
                        unsigned int h = (unsigned int)col / 192u;
                        unsigned int d = (unsigned int)col - h * 192u;
                        ((bfu*)Cv)[((b_ * HH + h) * SS + s) * (long)QKD + d] = (bfu)f2bf(val);
                    } else {
                        C2[row * 640 + (col - 3072)] = (bfu)f2bf(val);
                    }
                } else {                  // MODE 4: V^T -> vt[b][h][v][s]
                    long h  = row >> 7;
                    long v  = row & 127;
                    long b_ = col >> 11;
                    long s  = col & 2047;
                    ((bfu*)Cv)[(((b_ * HH + h) * VD) + v) * SS + s] = (bfu)f2bf(val);
                }
            }
}

// ---------------- merged: in-place RoPE on qr pe-cols + kall pe fill ----------------
__global__ void rope_pe_fill(bfu* __restrict__ qr, const bfu* __restrict__ kpe,
                             bfu* __restrict__ kall,
                             const float* __restrict__ fc, const float* __restrict__ fs) {
    long t = (long)blockIdx.x * 256 + threadIdx.x;
    int  ch = (int)(t & 7);
    long r  = t >> 3;
    int  s  = (int)(r & 2047);
    long bh = (r >> 11) & 63;
    long b_ = bh >> 4;
    if (t < 1048576L) {
        bfu* p = qr + (bh * SS + s) * (long)QKD + NOPE + ch * 8;
        bf16x8 v = *(const bf16x8*)p;
        int i0 = ch * 4;
        unsigned int out[4];
#pragma unroll
        for (int k = 0; k < 4; ++k) {
            float e = bf2f((unsigned short)v[2 * k]);
            float o = bf2f((unsigned short)v[2 * k + 1]);
            float c = fc[s * 32 + i0 + k], sn = fs[s * 32 + i0 + k];
            out[k] = cvt_pk_bf16(e * c - o * sn, e * sn + o * c);
        }
        *(uint4*)p = make_uint4(out[0], out[1], out[2], out[3]);
    } else {
        bf16x8 v = *(const bf16x8*)(kpe + (b_ * SS + s) * (long)ROPE + ch * 8);
        *(bf16x8*)(kall + (bh * SS + s) * (long)QKD + NOPE + ch * 8) = v;
    }
}

// ---------------- RMSNorm(kv_c) + RoPE(k_pe), one block per (b,s) row ----------------
__global__ void __launch_bounds__(256)
rms_rope_kv(const bfu* __restrict__ kv1, const float* __restrict__ wn,
            bfu* __restrict__ kvc, bfu* __restrict__ kpe,
            const float* __restrict__ fc, const float* __restrict__ fs) {
    const int row = blockIdx.x;            // b*S + s
    const int t   = threadIdx.x;
    const int s   = row & (SS - 1);
    const long base = (long)row * 640;
    unsigned int v = *(const unsigned int*)(kv1 + base + 2 * t);
    float a = bf2f(v & 0xffff), c2 = bf2f(v >> 16);
    float ssum = a * a + c2 * c2;
#pragma unroll
    for (int d = 1; d < 64; d <<= 1) ssum += __shfl_xor(ssum, d);
    __shared__ float red[4];
    const int lane = t & 63, w = t >> 6;
    if (lane == 0) red[w] = ssum;
    __syncthreads();
    float tot = red[0] + red[1] + red[2] + red[3];
    float scale = rsqrtf(tot * (1.0f / 512.0f) + 1e-6f);
    float w0 = wn[2 * t], w1 = wn[2 * t + 1];
    unsigned int out = f2bf(a * scale * w0) | (f2bf(c2 * scale * w1) << 16);
    *(unsigned int*)(kvc + (long)row * KVR + 2 * t) = out;
    if (t < 32) {
        unsigned int pv = *(const unsigned int*)(kv1 + base + KVR + 2 * t);
        float e = bf2f(pv & 0xffff), o = bf2f(pv >> 16);
        float cc = fc[s * 32 + t], sn = fs[s * 32 + t];
        unsigned int po = f2bf(e * cc - o * sn) | (f2bf(e * sn + o * cc) << 16);
        *(unsigned int*)(kpe + (long)row * ROPE + 2 * t) = po;
    }
}

// ---------------- flash causal attention v14 (R13 + setprio) ----------------
// 8 waves x 16 q-rows, tile-64 conflict-free LDS layout, double-buffered
// global_load_lds staging (stage(t+1) before compute(t), vmcnt(0) after),
// one barrier per tile. s_setprio(1) around MFMA clusters (T5).
template <bool MASKED>
__device__ __forceinline__ void attn_tile64(
    const char* kbuf, const char* vbuf, char* pw,
    const bf16x8 (&qf)[6], f32x4 (&accv)[8],
    float& ms, float& ls, int kv0, int qa, int ql, int kg, int lane) {
    // ---- QK^T from LDS: C[kv][q] ----
    f32x4 sc[4] = {};
    __builtin_amdgcn_s_setprio(1);
#pragma unroll
    for (int j = 0; j < 4; ++j)
#pragma unroll
        for (int d = 0; d < 6; ++d) {
            int row  = j * 16 + ql;
            int slot = (d * 4 + kg) ^ (ql & 7);
            bf16x8 kf = *(const bf16x8*)(kbuf + row * 384 + slot * 16);
            sc[j] = __builtin_amdgcn_mfma_f32_16x16x32_bf16(kf, qf[d], sc[j], 0, 0, 0);
        }
    __builtin_amdgcn_s_setprio(0);
    // ---- online softmax (q = ql lane-local column; Q pre-scaled, exp2 domain) ----
    float p[4][4];
    float mx = -1e30f;
#pragma unroll
    for (int j = 0; j < 4; ++j)
#pragma unroll
        for (int r = 0; r < 4; ++r) {
            float s = sc[j][r];
            if (MASKED) {
                int kv = kv0 + j * 16 + kg * 4 + r;
                s = (kv > qa) ? -1e30f : s;
            }
            p[j][r] = s;
            mx = fmaxf(mx, s);
        }
    mx = fmaxf(mx, __shfl_xor(mx, 16));
    mx = fmaxf(mx, __shfl_xor(mx, 32));
    float rs = 0.f;
    if (__all(mx <= ms)) {            // defer-max: running max unchanged, no rescale
#pragma unroll
        for (int j = 0; j < 4; ++j)
#pragma unroll
            for (int r = 0; r < 4; ++r) {
                float e = exp2f(p[j][r] - ms);
                p[j][r] = e;
                rs += e;
            }
        rs += __shfl_xor(rs, 16);
        rs += __shfl_xor(rs, 32);
        ls += rs;
    } else {
        float mn = fmaxf(ms, mx);
        float al = exp2f(ms - mn);
        ms = mn;
#pragma unroll
        for (int j = 0; j < 4; ++j)
#pragma unroll
            for (int r = 0; r < 4; ++r) {
                float e = exp2f(p[j][r] - mn);
                p[j][r] = e;
                rs += e;
            }
        rs += __shfl_xor(rs, 16);
        rs += __shfl_xor(rs, 32);
        ls = ls * al + rs;
        float alT[4];
#pragma unroll
        for (int r = 0; r < 4; ++r)
            alT[r] = __shfl(al, (lane & 48) + kg * 4 + r);
#pragma unroll
        for (int v8 = 0; v8 < 8; ++v8)
#pragma unroll
            for (int r = 0; r < 4; ++r)
                accv[v8][r] *= alT[r];
    }
    // ---- repack P -> wave LDS [16 q][64 kv], swizzled; cvt_pk packing ----
#pragma unroll
    for (int j = 0; j < 4; ++j) {
        uint2 u;
        u.x = cvt_pk_bf16(p[j][0], p[j][1]);
        u.y = cvt_pk_bf16(p[j][2], p[j][3]);
        int slot = (2 * j + (kg >> 1)) ^ (ql & 7);
        *(uint2*)(pw + ql * 128 + slot * 16 + (kg & 1) * 8) = u;
    }
    asm volatile("s_waitcnt lgkmcnt(0)" ::: "memory");
    // ---- PV from LDS: out[q][v] += P V ----
    __builtin_amdgcn_s_setprio(1);
#pragma unroll
    for (int t2 = 0; t2 < 2; ++t2) {
        int ps = (t2 * 4 + kg) ^ (ql & 7);
        bf16x8 pa = *(const bf16x8*)(pw + ql * 128 + ps * 16);
#pragma unroll
        for (int v8 = 0; v8 < 8; ++v8) {
            int vrow = v8 * 16 + ql;
            int vs   = (t2 * 4 + kg) ^ (ql & 7);
            bf16x8 vf = *(const bf16x8*)(vbuf + vrow * 128 + vs * 16);
            accv[v8] = __builtin_amdgcn_mfma_f32_16x16x32_bf16(pa, vf, accv[v8], 0, 0, 0);
        }
    }
    __builtin_amdgcn_s_setprio(0);
}

__global__ void __launch_bounds__(512)
attn(const bfu* __restrict__ qr, const bfu* __restrict__ kall,
     const bfu* __restrict__ vt, bfu* __restrict__ ao) {
    __shared__ __align__(16) char kbuf[2][64 * 384];   // 2 x 24576
    __shared__ __align__(16) char vbuf[2][128 * 128];  // 2 x 16384
    __shared__ __align__(16) char pbuf[8][2048];       // 16384 -> 98304 total
    const int tid  = threadIdx.x;
    const int lane = tid & 63;
    const int w    = tid >> 6;           // 0..7
    const int ql   = lane & 15;
    const int kg   = lane >> 4;
    const int bid  = blockIdx.x;
    const int qb   = 15 - (bid >> 6);    // longest blocks first
    const int bh   = bid & 63;
    const int h    = bh & 15;
    const int b    = bh >> 4;
    const char* Q  = (const char*)(qr + (long)bh * SS * QKD);
    const char* Kp = (const char*)(kall + (long)bh * SS * QKD);
    const char* Vp = (const char*)(vt + (long)bh * VD * SS);
    char* pw = pbuf[w];

    const int qa_min = qb * 128 + w * 16;
    const int qa = qa_min + ql;

    // ---- hoisted staging descriptors (K: 3 chunks, V: 2 chunks per thread) ----
    const char* ksrc[3]; int kdst[3];
#pragma unroll
    for (int i = 0; i < 3; ++i) {
        int idx  = i * 512 + tid;
        int row  = idx / 24;
        int slot = idx - row * 24;
        int ss   = slot ^ (row & 7);
        ksrc[i]  = Kp + (long)row * 384 + ss * 16;
        kdst[i]  = idx * 16;
    }
    const char* vsrc[2]; int vdst[2];
#pragma unroll
    for (int i = 0; i < 2; ++i) {
        int idx  = i * 512 + tid;
        int row  = idx >> 3;
        int slot = idx & 7;
        int ss   = slot ^ (row & 7);
        vsrc[i]  = Vp + (long)row * (SS * 2) + ss * 16;
        vdst[i]  = idx * 16;
    }
    auto stage = [&](int bi, int kv0) {
        const long ko = (long)kv0 * 384;
        const long vo = (long)kv0 * 2;
#pragma unroll
        for (int i = 0; i < 3; ++i)
            __builtin_amdgcn_global_load_lds((GV*)(ksrc[i] + ko), (LV*)(kbuf[bi] + kdst[i]), 16, 0, 0);
#pragma unroll
        for (int i = 0; i < 2; ++i)
            __builtin_amdgcn_global_load_lds((GV*)(vsrc[i] + vo), (LV*)(vbuf[bi] + vdst[i]), 16, 0, 0);
    };

    // ---- Q fragments (pre-scaled by log2(e)/sqrt(192) via wq cast) ----
    bf16x8 qf[6];
#pragma unroll
    for (int d = 0; d < 6; ++d)
        qf[d] = *(const bf16x8*)(Q + (long)(qa_min + ql) * 384 + d * 64 + kg * 16);

    f32x4 accv[8] = {};
    float ms = -1e30f, ls = 0.f;
    const int ntiles = 2 * qb + 2;

    stage(0, 0);                         // prologue prefetch
    __syncthreads();                     // drains vmcnt(0): buf0 ready

    for (int t = 0; t < ntiles; ++t) {
        const int cur = t & 1;
        const int kv0 = t * 64;
        if (t + 1 < ntiles)
            stage(cur ^ 1, kv0 + 64);    // issue next tile; latency hides under compute
        if (kv0 + 63 <= qa_min)          // fully unmasked
            attn_tile64<false>(kbuf[cur], vbuf[cur], pw, qf, accv, ms, ls, kv0, qa, ql, kg, lane);
        else if (kv0 <= qa_min + 15)     // diagonal
            attn_tile64<true>(kbuf[cur], vbuf[cur], pw, qf, accv, ms, ls, kv0, qa, ql, kg, lane);
        // else fully masked -> skip compute (still stages + barriers)
        asm volatile("s_waitcnt vmcnt(0)" ::: "memory");   // own t+1 loads landed
        __builtin_amdgcn_s_barrier();    // all waves: loads landed + done reading buf[cur]
        asm volatile("" ::: "memory");
    }
    // ---- epilogue ----
    float li[4];
#pragma unroll
    for (int r = 0; r < 4; ++r)
        li[r] = 1.0f / __shfl(ls, (lane & 48) + kg * 4 + r);
#pragma unroll
    for (int v8 = 0; v8 < 8; ++v8)
#pragma unroll
        for (int r = 0; r < 4; ++r) {
            float o = accv[v8][r] * li[r];
            long row = (long)b * SS + qa_min + kg * 4 + r;
            ao[row * (long)(HH * VD) + h * VD + v8 * 16 + ql] = (bfu)f2bf(o);
        }
}

// ---------------- workspace layout (bytes) ----------------
#define O_XB   0L                     // x bf16 33,554,432      (later: vt alias)
#define O_WQ   33554432L              // wq bf16 12,582,912 (scaled by SCL2)
#define O_WA   46137344L              // wkv_a padded 2,621,440 (contiguous after wq)
#define O_WKB  48758784L              // wkv_b K-part [2048][512] 2,097,152
#define O_WVB  50855936L              // wkv_b V-part [2048][512] 2,097,152
#define O_WO   52953088L              // wo 8,388,608
#define O_KALL 61341696L              // K assembled 50,331,648
#define O_KV1  111673344L             // kv_a compact out 8192x640 bf16 = 10,485,760
#define O_QR   122159104L             // q rope-layout 50,331,648 (written by proj1)
#define O_KVC  172490752L             // kv_c 8,388,608
#define O_KPE  180879360L             // k_pe 1,048,576
#define O_AO   181927936L             // attn out 33,554,432
#define WS_NEED 215482368L

extern "C" void kernel_launch(void* const* d_in, const int* in_sizes, int n_in,
                              void* d_out, int out_size, void* d_ws, size_t ws_size,
                              hipStream_t stream) {
    const float* x      = (const float*)d_in[0];
    const float* wq     = (const float*)d_in[1];
    const float* wkv_a  = (const float*)d_in[2];
    const float* kvnw   = (const float*)d_in[3];
    const float* wkv_b  = (const float*)d_in[4];
    const float* wo     = (const float*)d_in[5];
    const float* fcos   = (const float*)d_in[6];
    const float* fsin   = (const float*)d_in[7];
    if (ws_size < (size_t)WS_NEED) return;

    char* ws = (char*)d_ws;
    bfu* xb   = (bfu*)(ws + O_XB);
    bfu* wqb  = (bfu*)(ws + O_WQ);
    bfu* wab  = (bfu*)(ws + O_WA);
    bfu* wkb  = (bfu*)(ws + O_WKB);
    bfu* wvb  = (bfu*)(ws + O_WVB);
    bfu* wob  = (bfu*)(ws + O_WO);
    bfu* kall = (bfu*)(ws + O_KALL);
    bfu* kv1  = (bfu*)(ws + O_KV1);
    bfu* qr   = (bfu*)(ws + O_QR);
    bfu* kvc  = (bfu*)(ws + O_KVC);
    bfu* kpe  = (bfu*)(ws + O_KPE);
    bfu* ao   = (bfu*)(ws + O_AO);
    bfu* vt   = xb;                   // alias (xb dead after proj1 GEMM)
    (void)wab;

    // 1. all casts in one dispatch (x, wq*SCL2, wkv_a+pad, wkv_b->wkb/wvb, wo)
    cast_all<<<29952, 256, 0, stream>>>(x, wq, wkv_a, wkv_b, wo,
                                        xb, wqb, wab, wkb, wvb, wob);

    // 2. merged projection: [q | kv_a]; epilogue writes qr layout + compact kv1
    gemm_bt<3><<<dim3(29, 64), 256, 0, stream>>>(xb, wqb, qr, kv1, NP1, DD);

    // 3. rmsnorm + k_pe rope (reads compact kv1)
    rms_rope_kv<<<ROWS, 256, 0, stream>>>(kv1, kvnw, kvc, kpe, fcos, fsin);

    // 4. kv_b K-part: kvc @ wkb^T -> kall (nope cols)
    gemm_bt<2><<<dim3(16, 64), 256, 0, stream>>>(kvc, wkb, nullptr, kall, 2048, KVR);

    // 5. V^T GEMM: wvb @ kvc^T -> vt[b][h][v][s] directly (no transpose kernel)
    gemm_bt<4><<<dim3(64, 16), 256, 0, stream>>>(wvb, kvc, vt, nullptr, 8192, KVR);

    // 6. in-place q-pe rope + kall pe fill (merged)
    rope_pe_fill<<<8192, 256, 0, stream>>>(qr, kpe, kall, fcos, fsin);

    // 7. attention (1024 blocks x 512 threads: 64 bh x 16 q-tiles, 8 waves/block)
    attn<<<1024, 512, 0, stream>>>(qr, kall, vt, ao);

    // 8. output projection (fp32 out)
    gemm_bt<1><<<dim3(16, 64), 256, 0, stream>>>(ao, wob, d_out, nullptr, DD, HH * VD);
}

// Round 15
// 513.028 us; speedup vs baseline: 1.0003x; 1.0003x over previous
//
#include <hip/hip_runtime.h>
#include <math.h>

// ---------------- problem constants ----------------
#define BB 4
#define SS 2048
#define DD 2048
#define HH 16
#define NOPE 128
#define ROPE 64
#define VD 128
#define QKD 192         // NOPE+ROPE
#define KVR 512
#define NP1 3712        // merged proj1 width: 3072 (q) + 640 (kv_a padded)
#define ROWS (BB*SS)    // 8192
// log2(e) / sqrt(192), folded into wq at cast time
#define SCL2 0.1041216338380858f

typedef __attribute__((ext_vector_type(8))) short bf16x8;
typedef __attribute__((ext_vector_type(4))) float f32x4;
typedef unsigned short bfu;
typedef __attribute__((address_space(1))) const void GV;
typedef __attribute__((address_space(3))) void LV;

__device__ __forceinline__ float bf2f(unsigned int u) {
    unsigned int i = u << 16; float f; __builtin_memcpy(&f, &i, 4); return f;
}
__device__ __forceinline__ unsigned int f2bf(float f) {
    unsigned int i; __builtin_memcpy(&i, &f, 4);
    return (i + 0x7fffu + ((i >> 16) & 1u)) >> 16;
}
__device__ __forceinline__ unsigned int cvt_pk_bf16(float lo, float hi) {
    unsigned int r;
    asm("v_cvt_pk_bf16_f32 %0, %1, %2" : "=v"(r) : "v"(lo), "v"(hi));
    return r;
}

// ---------------- one fused cast: x | wq*SCL2 | wkv_a(+pad) | wkv_b(->wkb/wvb) | wo ----------------
__global__ void cast_all(const float* __restrict__ x, const float* __restrict__ wq,
                         const float* __restrict__ wa, const float* __restrict__ wb,
                         const float* __restrict__ wo,
                         bfu* __restrict__ dx, bfu* __restrict__ dq,
                         bfu* __restrict__ da, bfu* __restrict__ dkb,
                         bfu* __restrict__ dvb, bfu* __restrict__ dwo) {
    long i = (long)blockIdx.x * 256 + threadIdx.x;   // one float4 each
    const float* src; bfu* dst; long off, n_src; float scl = 1.0f;
    if (i < 4194304L)        { src = x;  dst = dx;  off = i;            n_src = 4194304L; }
    else if (i < 5767168L)   { src = wq; dst = dq;  off = i - 4194304L; n_src = 1572864L; scl = SCL2; }
    else if (i < 6094848L)   { src = wa; dst = da;  off = i - 5767168L; n_src = 294912L;  }
    else if (i < 6619136L)   {          // wkv_b: split K-rows / V-rows
        long off2 = i - 6094848L;       // float4 index into wkv_b [4096][128]
        long row = off2 >> 7, c = off2 & 127;
        long h = row >> 8, wi = row & 255;
        bfu* d2 = (wi < 128) ? dkb : dvb;
        long drow = (h << 7) + (wi & 127);
        float4 v = ((const float4*)wb)[off2];
        unsigned int lo = f2bf(v.x) | (f2bf(v.y) << 16);
        unsigned int hi = f2bf(v.z) | (f2bf(v.w) << 16);
        ((uint2*)d2)[drow * 128 + c] = make_uint2(lo, hi);
        return;
    }
    else if (i < 7667712L)   { src = wo; dst = dwo; off = i - 6619136L; n_src = 1048576L; }
    else return;
    unsigned int lo = 0, hi = 0;
    if (off < n_src) {
        float4 v = ((const float4*)src)[off];
        lo = f2bf(v.x * scl) | (f2bf(v.y * scl) << 16);
        hi = f2bf(v.z * scl) | (f2bf(v.w * scl) << 16);
    }
    ((uint2*)dst)[off] = make_uint2(lo, hi);
}

// ---------------- 128x128 tile bf16 GEMM, C = A[M,K] @ Bt[N,K]^T ----------------
// MODE 1: f32 out to Cv.
// MODE 2 (kv_b K-part, N=2048): col=h*128+d -> kall (C2).
// MODE 3 (proj1, N=3712): col<3072 -> qr rope-layout (Cv); col>=3072 -> kv1 [row][640] (C2).
// MODE 4 (V^T, M=2048, N=8192): row=h*128+v, col=b*2048+s -> vt[b][h][v][s] (Cv).
// XCD-aware bijective block swizzle (grid size always % 8 == 0 here).
template <int MODE>
__global__ void __launch_bounds__(256)
gemm_bt(const bfu* __restrict__ A, const bfu* __restrict__ Bt,
        void* __restrict__ Cv, bfu* __restrict__ C2, int N, int K) {
    __shared__ __align__(16) char lds[32768];
    char* AsB = lds;
    char* BsB = lds + 16384;
    const int tid  = threadIdx.x;
    const int lane = tid & 63;
    const int wid  = tid >> 6;
    const int wr   = wid >> 1, wc = wid & 1;
    const int nwg  = gridDim.x * gridDim.y;
    const int flat = blockIdx.y * gridDim.x + blockIdx.x;
    const int swz  = (flat & 7) * (nwg >> 3) + (flat >> 3);
    const long m0 = (long)(swz / gridDim.x) * 128;
    const long n0 = (long)(swz % gridDim.x) * 128;

    f32x4 acc[4][4] = {};

    const int lr = lane >> 3;            // row within 8-row stripe
    const int SB = (lane & 7) << 4;      // 16B slot within 128B row

    for (int k0 = 0; k0 < K; k0 += 64) {
        __syncthreads();
#pragma unroll
        for (int i = 0; i < 4; ++i) {
            int rb = wid * 32 + i * 8;   // wave-uniform row base
            int R  = rb + lr;
            int c  = (SB ^ ((R & 7) << 4)) >> 1;   // pre-swizzled source column
            const bfu* gA = A  + (m0 + R) * (long)K + k0 + c;
            const bfu* gB = Bt + (n0 + R) * (long)K + k0 + c;
            __builtin_amdgcn_global_load_lds((GV*)gA, (LV*)(AsB + rb * 128), 16, 0, 0);
            __builtin_amdgcn_global_load_lds((GV*)gB, (LV*)(BsB + rb * 128), 16, 0, 0);
        }
        __syncthreads();
#pragma unroll
        for (int kk = 0; kk < 2; ++kk) {
            bf16x8 av[4], bv[4];
            const int cb = kk * 64 + ((lane >> 4) << 4);
#pragma unroll
            for (int m = 0; m < 4; ++m) {
                int R = wr * 64 + m * 16 + (lane & 15);
                av[m] = *(const bf16x8*)(AsB + R * 128 + (cb ^ ((R & 7) << 4)));
            }
#pragma unroll
            for (int n = 0; n < 4; ++n) {
                int R = wc * 64 + n * 16 + (lane & 15);
                bv[n] = *(const bf16x8*)(BsB + R * 128 + (cb ^ ((R & 7) << 4)));
            }
#pragma unroll
            for (int m = 0; m < 4; ++m)
#pragma unroll
                for (int n = 0; n < 4; ++n)
                    acc[m][n] = __builtin_amdgcn_mfma_f32_16x16x32_bf16(av[m], bv[n], acc[m][n], 0, 0, 0);
        }
    }

    const int cr = (lane >> 4) << 2;
    const int cc = lane & 15;
#pragma unroll
    for (int m = 0; m < 4; ++m)
#pragma unroll
        for (int n = 0; n < 4; ++n)
#pragma unroll
            for (int r = 0; r < 4; ++r) {
                long row = m0 + wr * 64 + m * 16 + cr + r;
                long col = n0 + wc * 64 + n * 16 + cc;
                float val = acc[m][n][r];
                if (MODE == 1) {
                    ((float*)Cv)[row * N + col] = val;
                } else if (MODE == 2) {   // kv_b K-part: col = h*128+d
                    long b_ = row >> 11;
                    long s  = row & 2047;
                    long h  = col >> 7;
                    long d  = col & 127;
                    C2[((b_ * HH + h) * SS + s) * (long)QKD + d] = (bfu)f2bf(val);
                } else if (MODE == 3) {   // proj1 split (N==3712)
                    long b_ = row >> 11;
                    long s  = row & 2047;
                    if (col < 3072) {
                        unsigned int h = (unsigned int)col / 192u;
                        unsigned int d = (unsigned int)col - h * 192u;
                        ((bfu*)Cv)[((b_ * HH + h) * SS + s) * (long)QKD + d] = (bfu)f2bf(val);
                    } else {
                        C2[row * 640 + (col - 3072)] = (bfu)f2bf(val);
                    }
                } else {                  // MODE 4: V^T -> vt[b][h][v][s]
                    long h  = row >> 7;
                    long v  = row & 127;
                    long b_ = col >> 11;
                    long s  = col & 2047;
                    ((bfu*)Cv)[(((b_ * HH + h) * VD) + v) * SS + s] = (bfu)f2bf(val);
                }
            }
}

// ---------------- merged: in-place RoPE on qr pe-cols + kall pe fill ----------------
__global__ void rope_pe_fill(bfu* __restrict__ qr, const bfu* __restrict__ kpe,
                             bfu* __restrict__ kall,
                             const float* __restrict__ fc, const float* __restrict__ fs) {
    long t = (long)blockIdx.x * 256 + threadIdx.x;
    int  ch = (int)(t & 7);
    long r  = t >> 3;
    int  s  = (int)(r & 2047);
    long bh = (r >> 11) & 63;
    long b_ = bh >> 4;
    if (t < 1048576L) {
        bfu* p = qr + (bh * SS + s) * (long)QKD + NOPE + ch * 8;
        bf16x8 v = *(const bf16x8*)p;
        int i0 = ch * 4;
        unsigned int out[4];
#pragma unroll
        for (int k = 0; k < 4; ++k) {
            float e = bf2f((unsigned short)v[2 * k]);
            float o = bf2f((unsigned short)v[2 * k + 1]);
            float c = fc[s * 32 + i0 + k], sn = fs[s * 32 + i0 + k];
            out[k] = cvt_pk_bf16(e * c - o * sn, e * sn + o * c);
        }
        *(uint4*)p = make_uint4(out[0], out[1], out[2], out[3]);
    } else {
        bf16x8 v = *(const bf16x8*)(kpe + (b_ * SS + s) * (long)ROPE + ch * 8);
        *(bf16x8*)(kall + (bh * SS + s) * (long)QKD + NOPE + ch * 8) = v;
    }
}

// ---------------- RMSNorm(kv_c) + RoPE(k_pe), one block per (b,s) row ----------------
__global__ void __launch_bounds__(256)
rms_rope_kv(const bfu* __restrict__ kv1, const float* __restrict__ wn,
            bfu* __restrict__ kvc, bfu* __restrict__ kpe,
            const float* __restrict__ fc, const float* __restrict__ fs) {
    const int row = blockIdx.x;            // b*S + s
    const int t   = threadIdx.x;
    const int s   = row & (SS - 1);
    const long base = (long)row * 640;
    unsigned int v = *(const unsigned int*)(kv1 + base + 2 * t);
    float a = bf2f(v & 0xffff), c2 = bf2f(v >> 16);
    float ssum = a * a + c2 * c2;
#pragma unroll
    for (int d = 1; d < 64; d <<= 1) ssum += __shfl_xor(ssum, d);
    __shared__ float red[4];
    const int lane = t & 63, w = t >> 6;
    if (lane == 0) red[w] = ssum;
    __syncthreads();
    float tot = red[0] + red[1] + red[2] + red[3];
    float scale = rsqrtf(tot * (1.0f / 512.0f) + 1e-6f);
    float w0 = wn[2 * t], w1 = wn[2 * t + 1];
    unsigned int out = f2bf(a * scale * w0) | (f2bf(c2 * scale * w1) << 16);
    *(unsigned int*)(kvc + (long)row * KVR + 2 * t) = out;
    if (t < 32) {
        unsigned int pv = *(const unsigned int*)(kv1 + base + KVR + 2 * t);
        float e = bf2f(pv & 0xffff), o = bf2f(pv >> 16);
        float cc = fc[s * 32 + t], sn = fs[s * 32 + t];
        unsigned int po = f2bf(e * cc - o * sn) | (f2bf(e * sn + o * cc) << 16);
        *(unsigned int*)(kpe + (long)row * ROPE + 2 * t) = po;
    }
}

// ---------------- flash causal attention v15 (== R13's best: no setprio) ----------------
// 8 waves x 16 q-rows, tile-64 conflict-free LDS layout, double-buffered
// global_load_lds staging (stage(t+1) before compute(t), vmcnt(0) after),
// one barrier per tile.
template <bool MASKED>
__device__ __forceinline__ void attn_tile64(
    const char* kbuf, const char* vbuf, char* pw,
    const bf16x8 (&qf)[6], f32x4 (&accv)[8],
    float& ms, float& ls, int kv0, int qa, int ql, int kg, int lane) {
    // ---- QK^T from LDS: C[kv][q] ----
    f32x4 sc[4] = {};
#pragma unroll
    for (int j = 0; j < 4; ++j)
#pragma unroll
        for (int d = 0; d < 6; ++d) {
            int row  = j * 16 + ql;
            int slot = (d * 4 + kg) ^ (ql & 7);
            bf16x8 kf = *(const bf16x8*)(kbuf + row * 384 + slot * 16);
            sc[j] = __builtin_amdgcn_mfma_f32_16x16x32_bf16(kf, qf[d], sc[j], 0, 0, 0);
        }
    // ---- online softmax (q = ql lane-local column; Q pre-scaled, exp2 domain) ----
    float p[4][4];
    float mx = -1e30f;
#pragma unroll
    for (int j = 0; j < 4; ++j)
#pragma unroll
        for (int r = 0; r < 4; ++r) {
            float s = sc[j][r];
            if (MASKED) {
                int kv = kv0 + j * 16 + kg * 4 + r;
                s = (kv > qa) ? -1e30f : s;
            }
            p[j][r] = s;
            mx = fmaxf(mx, s);
        }
    mx = fmaxf(mx, __shfl_xor(mx, 16));
    mx = fmaxf(mx, __shfl_xor(mx, 32));
    float rs = 0.f;
    if (__all(mx <= ms)) {            // defer-max: running max unchanged, no rescale
#pragma unroll
        for (int j = 0; j < 4; ++j)
#pragma unroll
            for (int r = 0; r < 4; ++r) {
                float e = exp2f(p[j][r] - ms);
                p[j][r] = e;
                rs += e;
            }
        rs += __shfl_xor(rs, 16);
        rs += __shfl_xor(rs, 32);
        ls += rs;
    } else {
        float mn = fmaxf(ms, mx);
        float al = exp2f(ms - mn);
        ms = mn;
#pragma unroll
        for (int j = 0; j < 4; ++j)
#pragma unroll
            for (int r = 0; r < 4; ++r) {
                float e = exp2f(p[j][r] - mn);
                p[j][r] = e;
                rs += e;
            }
        rs += __shfl_xor(rs, 16);
        rs += __shfl_xor(rs, 32);
        ls = ls * al + rs;
        float alT[4];
#pragma unroll
        for (int r = 0; r < 4; ++r)
            alT[r] = __shfl(al, (lane & 48) + kg * 4 + r);
#pragma unroll
        for (int v8 = 0; v8 < 8; ++v8)
#pragma unroll
            for (int r = 0; r < 4; ++r)
                accv[v8][r] *= alT[r];
    }
    // ---- repack P -> wave LDS [16 q][64 kv], swizzled; cvt_pk packing ----
#pragma unroll
    for (int j = 0; j < 4; ++j) {
        uint2 u;
        u.x = cvt_pk_bf16(p[j][0], p[j][1]);
        u.y = cvt_pk_bf16(p[j][2], p[j][3]);
        int slot = (2 * j + (kg >> 1)) ^ (ql & 7);
        *(uint2*)(pw + ql * 128 + slot * 16 + (kg & 1) * 8) = u;
    }
    asm volatile("s_waitcnt lgkmcnt(0)" ::: "memory");
    // ---- PV from LDS: out[q][v] += P V ----
#pragma unroll
    for (int t2 = 0; t2 < 2; ++t2) {
        int ps = (t2 * 4 + kg) ^ (ql & 7);
        bf16x8 pa = *(const bf16x8*)(pw + ql * 128 + ps * 16);
#pragma unroll
        for (int v8 = 0; v8 < 8; ++v8) {
            int vrow = v8 * 16 + ql;
            int vs   = (t2 * 4 + kg) ^ (ql & 7);
            bf16x8 vf = *(const bf16x8*)(vbuf + vrow * 128 + vs * 16);
            accv[v8] = __builtin_amdgcn_mfma_f32_16x16x32_bf16(pa, vf, accv[v8], 0, 0, 0);
        }
    }
}

__global__ void __launch_bounds__(512)
attn(const bfu* __restrict__ qr, const bfu* __restrict__ kall,
     const bfu* __restrict__ vt, bfu* __restrict__ ao) {
    __shared__ __align__(16) char kbuf[2][64 * 384];   // 2 x 24576
    __shared__ __align__(16) char vbuf[2][128 * 128];  // 2 x 16384
    __shared__ __align__(16) char pbuf[8][2048];       // 16384 -> 98304 total
    const int tid  = threadIdx.x;
    const int lane = tid & 63;
    const int w    = tid >> 6;           // 0..7
    const int ql   = lane & 15;
    const int kg   = lane >> 4;
    const int bid  = blockIdx.x;
    const int qb   = 15 - (bid >> 6);    // longest blocks first
    const int bh   = bid & 63;
    const int h    = bh & 15;
    const int b    = bh >> 4;
    const char* Q  = (const char*)(qr + (long)bh * SS * QKD);
    const char* Kp = (const char*)(kall + (long)bh * SS * QKD);
    const char* Vp = (const char*)(vt + (long)bh * VD * SS);
    char* pw = pbuf[w];

    const int qa_min = qb * 128 + w * 16;
    const int qa = qa_min + ql;

    // ---- hoisted staging descriptors (K: 3 chunks, V: 2 chunks per thread) ----
    const char* ksrc[3]; int kdst[3];
#pragma unroll
    for (int i = 0; i < 3; ++i) {
        int idx  = i * 512 + tid;
        int row  = idx / 24;
        int slot = idx - row * 24;
        int ss   = slot ^ (row & 7);
        ksrc[i]  = Kp + (long)row * 384 + ss * 16;
        kdst[i]  = idx * 16;
    }
    const char* vsrc[2]; int vdst[2];
#pragma unroll
    for (int i = 0; i < 2; ++i) {
        int idx  = i * 512 + tid;
        int row  = idx >> 3;
        int slot = idx & 7;
        int ss   = slot ^ (row & 7);
        vsrc[i]  = Vp + (long)row * (SS * 2) + ss * 16;
        vdst[i]  = idx * 16;
    }
    auto stage = [&](int bi, int kv0) {
        const long ko = (long)kv0 * 384;
        const long vo = (long)kv0 * 2;
#pragma unroll
        for (int i = 0; i < 3; ++i)
            __builtin_amdgcn_global_load_lds((GV*)(ksrc[i] + ko), (LV*)(kbuf[bi] + kdst[i]), 16, 0, 0);
#pragma unroll
        for (int i = 0; i < 2; ++i)
            __builtin_amdgcn_global_load_lds((GV*)(vsrc[i] + vo), (LV*)(vbuf[bi] + vdst[i]), 16, 0, 0);
    };

    // ---- Q fragments (pre-scaled by log2(e)/sqrt(192) via wq cast) ----
    bf16x8 qf[6];
#pragma unroll
    for (int d = 0; d < 6; ++d)
        qf[d] = *(const bf16x8*)(Q + (long)(qa_min + ql) * 384 + d * 64 + kg * 16);

    f32x4 accv[8] = {};
    float ms = -1e30f, ls = 0.f;
    const int ntiles = 2 * qb + 2;

    stage(0, 0);                         // prologue prefetch
    __syncthreads();                     // drains vmcnt(0): buf0 ready

    for (int t = 0; t < ntiles; ++t) {
        const int cur = t & 1;
        const int kv0 = t * 64;
        if (t + 1 < ntiles)
            stage(cur ^ 1, kv0 + 64);    // issue next tile; latency hides under compute
        if (kv0 + 63 <= qa_min)          // fully unmasked
            attn_tile64<false>(kbuf[cur], vbuf[cur], pw, qf, accv, ms, ls, kv0, qa, ql, kg, lane);
        else if (kv0 <= qa_min + 15)     // diagonal
            attn_tile64<true>(kbuf[cur], vbuf[cur], pw, qf, accv, ms, ls, kv0, qa, ql, kg, lane);
        // else fully masked -> skip compute (still stages + barriers)
        asm volatile("s_waitcnt vmcnt(0)" ::: "memory");   // own t+1 loads landed
        __builtin_amdgcn_s_barrier();    // all waves: loads landed + done reading buf[cur]
        asm volatile("" ::: "memory");
    }
    // ---- epilogue ----
    float li[4];
#pragma unroll
    for (int r = 0; r < 4; ++r)
        li[r] = 1.0f / __shfl(ls, (lane & 48) + kg * 4 + r);
#pragma unroll
    for (int v8 = 0; v8 < 8; ++v8)
#pragma unroll
        for (int r = 0; r < 4; ++r) {
            float o = accv[v8][r] * li[r];
            long row = (long)b * SS + qa_min + kg * 4 + r;
            ao[row * (long)(HH * VD) + h * VD + v8 * 16 + ql] = (bfu)f2bf(o);
        }
}

// ---------------- workspace layout (bytes) ----------------
#define O_XB   0L                     // x bf16 33,554,432      (later: vt alias)
#define O_WQ   33554432L              // wq bf16 12,582,912 (scaled by SCL2)
#define O_WA   46137344L              // wkv_a padded 2,621,440 (contiguous after wq)
#define O_WKB  48758784L              // wkv_b K-part [2048][512] 2,097,152
#define O_WVB  50855936L              // wkv_b V-part [2048][512] 2,097,152
#define O_WO   52953088L              // wo 8,388,608
#define O_KALL 61341696L              // K assembled 50,331,648
#define O_KV1  111673344L             // kv_a compact out 8192x640 bf16 = 10,485,760
#define O_QR   122159104L             // q rope-layout 50,331,648 (written by proj1)
#define O_KVC  172490752L             // kv_c 8,388,608
#define O_KPE  180879360L             // k_pe 1,048,576
#define O_AO   181927936L             // attn out 33,554,432
#define WS_NEED 215482368L

extern "C" void kernel_launch(void* const* d_in, const int* in_sizes, int n_in,
                              void* d_out, int out_size, void* d_ws, size_t ws_size,
                              hipStream_t stream) {
    const float* x      = (const float*)d_in[0];
    const float* wq     = (const float*)d_in[1];
    const float* wkv_a  = (const float*)d_in[2];
    const float* kvnw   = (const float*)d_in[3];
    const float* wkv_b  = (const float*)d_in[4];
    const float* wo     = (const float*)d_in[5];
    const float* fcos   = (const float*)d_in[6];
    const float* fsin   = (const float*)d_in[7];
    if (ws_size < (size_t)WS_NEED) return;

    char* ws = (char*)d_ws;
    bfu* xb   = (bfu*)(ws + O_XB);
    bfu* wqb  = (bfu*)(ws + O_WQ);
    bfu* wab  = (bfu*)(ws + O_WA);
    bfu* wkb  = (bfu*)(ws + O_WKB);
    bfu* wvb  = (bfu*)(ws + O_WVB);
    bfu* wob  = (bfu*)(ws + O_WO);
    bfu* kall = (bfu*)(ws + O_KALL);
    bfu* kv1  = (bfu*)(ws + O_KV1);
    bfu* qr   = (bfu*)(ws + O_QR);
    bfu* kvc  = (bfu*)(ws + O_KVC);
    bfu* kpe  = (bfu*)(ws + O_KPE);
    bfu* ao   = (bfu*)(ws + O_AO);
    bfu* vt   = xb;                   // alias (xb dead after proj1 GEMM)

    // 1. all casts in one dispatch (x, wq*SCL2, wkv_a+pad, wkv_b->wkb/wvb, wo)
    cast_all<<<29952, 256, 0, stream>>>(x, wq, wkv_a, wkv_b, wo,
                                        xb, wqb, wab, wkb, wvb, wob);

    // 2. merged projection: [q | kv_a]; epilogue writes qr layout + compact kv1
    gemm_bt<3><<<dim3(29, 64), 256, 0, stream>>>(xb, wqb, qr, kv1, NP1, DD);

    // 3. rmsnorm + k_pe rope (reads compact kv1)
    rms_rope_kv<<<ROWS, 256, 0, stream>>>(kv1, kvnw, kvc, kpe, fcos, fsin);

    // 4. kv_b K-part: kvc @ wkb^T -> kall (nope cols)
    gemm_bt<2><<<dim3(16, 64), 256, 0, stream>>>(kvc, wkb, nullptr, kall, 2048, KVR);

    // 5. V^T GEMM: wvb @ kvc^T -> vt[b][h][v][s] directly (no transpose kernel)
    gemm_bt<4><<<dim3(64, 16), 256, 0, stream>>>(wvb, kvc, vt, nullptr, 8192, KVR);

    // 6. in-place q-pe rope + kall pe fill (merged)
    rope_pe_fill<<<8192, 256, 0, stream>>>(qr, kpe, kall, fcos, fsin);

    // 7. attention (1024 blocks x 512 threads: 64 bh x 16 q-tiles, 8 waves/block)
    attn<<<1024, 512, 0, stream>>>(qr, kall, vt, ao);

    // 8. output projection (fp32 out)
    gemm_bt<1><<<dim3(16, 64), 256, 0, stream>>>(ao, wob, d_out, nullptr, DD, HH * VD);
}

// Round 16
// 472.834 us; speedup vs baseline: 1.0853x; 1.0850x over previous
//
#include <hip/hip_runtime.h>
#include <math.h>

// ---------------- problem constants ----------------
#define BB 4
#define SS 2048
#define DD 2048
#define HH 16
#define NOPE 128
#define ROPE 64
#define VD 128
#define QKD 192         // NOPE+ROPE
#define KVR 512
#define ROWS (BB*SS)    // 8192
// log2(e) / sqrt(192), folded into wq at cast time
#define SCL2 0.1041216338380858f

typedef __attribute__((ext_vector_type(8))) short bf16x8;
typedef __attribute__((ext_vector_type(4))) float f32x4;
typedef unsigned short bfu;
typedef __attribute__((address_space(1))) const void GV;
typedef __attribute__((address_space(3))) void LV;

__device__ __forceinline__ float bf2f(unsigned int u) {
    unsigned int i = u << 16; float f; __builtin_memcpy(&f, &i, 4); return f;
}
__device__ __forceinline__ unsigned int f2bf(float f) {
    unsigned int i; __builtin_memcpy(&i, &f, 4);
    return (i + 0x7fffu + ((i >> 16) & 1u)) >> 16;
}
__device__ __forceinline__ unsigned int cvt_pk_bf16(float lo, float hi) {
    unsigned int r;
    asm("v_cvt_pk_bf16_f32 %0, %1, %2" : "=v"(r) : "v"(lo), "v"(hi));
    return r;
}

// ---------------- one fused cast: x | wq*SCL2 | wkv_a(+pad) | wkv_b(->wkb/wvb) | wo ----------------
__global__ void cast_all(const float* __restrict__ x, const float* __restrict__ wq,
                         const float* __restrict__ wa, const float* __restrict__ wb,
                         const float* __restrict__ wo,
                         bfu* __restrict__ dx, bfu* __restrict__ dq,
                         bfu* __restrict__ da, bfu* __restrict__ dkb,
                         bfu* __restrict__ dvb, bfu* __restrict__ dwo) {
    long i = (long)blockIdx.x * 256 + threadIdx.x;   // one float4 each
    const float* src; bfu* dst; long off, n_src; float scl = 1.0f;
    if (i < 4194304L)        { src = x;  dst = dx;  off = i;            n_src = 4194304L; }
    else if (i < 5767168L)   { src = wq; dst = dq;  off = i - 4194304L; n_src = 1572864L; scl = SCL2; }
    else if (i < 6094848L)   { src = wa; dst = da;  off = i - 5767168L; n_src = 294912L;  }
    else if (i < 6619136L)   {          // wkv_b: split K-rows / V-rows
        long off2 = i - 6094848L;       // float4 index into wkv_b [4096][128]
        long row = off2 >> 7, c = off2 & 127;
        long h = row >> 8, wi = row & 255;
        bfu* d2 = (wi < 128) ? dkb : dvb;
        long drow = (h << 7) + (wi & 127);
        float4 v = ((const float4*)wb)[off2];
        unsigned int lo = f2bf(v.x) | (f2bf(v.y) << 16);
        unsigned int hi = f2bf(v.z) | (f2bf(v.w) << 16);
        ((uint2*)d2)[drow * 128 + c] = make_uint2(lo, hi);
        return;
    }
    else if (i < 7667712L)   { src = wo; dst = dwo; off = i - 6619136L; n_src = 1048576L; }
    else return;
    unsigned int lo = 0, hi = 0;
    if (off < n_src) {
        float4 v = ((const float4*)src)[off];
        lo = f2bf(v.x * scl) | (f2bf(v.y * scl) << 16);
        hi = f2bf(v.z * scl) | (f2bf(v.w * scl) << 16);
    }
    ((uint2*)dst)[off] = make_uint2(lo, hi);
}

// ---------------- 128x128 tile bf16 GEMM (proven m97 structure) ----------------
// MODE 0: bf16 linear out. MODE 2 (kv_b K-part, N=2048): col=h*128+d -> kall (C2).
// MODE 4 (V^T, M=2048, N=8192): row=h*128+v, col=b*2048+s -> vt[b][h][v][s] (Cv).
template <int MODE>
__global__ void __launch_bounds__(256)
gemm_bt(const bfu* __restrict__ A, const bfu* __restrict__ Bt,
        void* __restrict__ Cv, bfu* __restrict__ C2, int N, int K) {
    __shared__ __align__(16) char lds[32768];
    char* AsB = lds;
    char* BsB = lds + 16384;
    const int tid  = threadIdx.x;
    const int lane = tid & 63;
    const int wid  = tid >> 6;
    const int wr   = wid >> 1, wc = wid & 1;
    const int nwg  = gridDim.x * gridDim.y;
    const int flat = blockIdx.y * gridDim.x + blockIdx.x;
    const int swz  = (flat & 7) * (nwg >> 3) + (flat >> 3);
    const long m0 = (long)(swz / gridDim.x) * 128;
    const long n0 = (long)(swz % gridDim.x) * 128;

    f32x4 acc[4][4] = {};

    const int lr = lane >> 3;            // row within 8-row stripe
    const int SB = (lane & 7) << 4;      // 16B slot within 128B row

    for (int k0 = 0; k0 < K; k0 += 64) {
        __syncthreads();
#pragma unroll
        for (int i = 0; i < 4; ++i) {
            int rb = wid * 32 + i * 8;   // wave-uniform row base
            int R  = rb + lr;
            int c  = (SB ^ ((R & 7) << 4)) >> 1;   // pre-swizzled source column
            const bfu* gA = A  + (m0 + R) * (long)K + k0 + c;
            const bfu* gB = Bt + (n0 + R) * (long)K + k0 + c;
            __builtin_amdgcn_global_load_lds((GV*)gA, (LV*)(AsB + rb * 128), 16, 0, 0);
            __builtin_amdgcn_global_load_lds((GV*)gB, (LV*)(BsB + rb * 128), 16, 0, 0);
        }
        __syncthreads();
#pragma unroll
        for (int kk = 0; kk < 2; ++kk) {
            bf16x8 av[4], bv[4];
            const int cb = kk * 64 + ((lane >> 4) << 4);
#pragma unroll
            for (int m = 0; m < 4; ++m) {
                int R = wr * 64 + m * 16 + (lane & 15);
                av[m] = *(const bf16x8*)(AsB + R * 128 + (cb ^ ((R & 7) << 4)));
            }
#pragma unroll
            for (int n = 0; n < 4; ++n) {
                int R = wc * 64 + n * 16 + (lane & 15);
                bv[n] = *(const bf16x8*)(BsB + R * 128 + (cb ^ ((R & 7) << 4)));
            }
#pragma unroll
            for (int m = 0; m < 4; ++m)
#pragma unroll
                for (int n = 0; n < 4; ++n)
                    acc[m][n] = __builtin_amdgcn_mfma_f32_16x16x32_bf16(av[m], bv[n], acc[m][n], 0, 0, 0);
        }
    }

    const int cr = (lane >> 4) << 2;
    const int cc = lane & 15;
#pragma unroll
    for (int m = 0; m < 4; ++m)
#pragma unroll
        for (int n = 0; n < 4; ++n)
#pragma unroll
            for (int r = 0; r < 4; ++r) {
                long row = m0 + wr * 64 + m * 16 + cr + r;
                long col = n0 + wc * 64 + n * 16 + cc;
                float val = acc[m][n][r];
                if (MODE == 0) {
                    ((bfu*)Cv)[row * N + col] = (bfu)f2bf(val);
                } else if (MODE == 2) {   // kv_b K-part: col = h*128+d
                    long b_ = row >> 11;
                    long s  = row & 2047;
                    long h  = col >> 7;
                    long d  = col & 127;
                    C2[((b_ * HH + h) * SS + s) * (long)QKD + d] = (bfu)f2bf(val);
                } else {                  // MODE 4: V^T -> vt[b][h][v][s]
                    long h  = row >> 7;
                    long v  = row & 127;
                    long b_ = col >> 11;
                    long s  = col & 2047;
                    ((bfu*)Cv)[(((b_ * HH + h) * VD) + v) * SS + s] = (bfu)f2bf(val);
                }
            }
}

// ---------------- 256x256 tile bf16 GEMM, 8 waves, 4-phase dbuf pipeline ----------------
// MODE 0: q-proj epilogue -> qr rope-layout (col=h*192+d). MODE 1: f32 linear out.
// LDS 128 KB: A[2 buf][2 half][128][64], B likewise. Stage of K-tile kt+1 spread
// over the 4 phases of computing kt (targets buf^1 -> no intra-tile hazard);
// one vmcnt(0)+barrier per K-tile boundary (loads drained were issued >=1 phase ago).
template <int MODE>
__global__ void __launch_bounds__(512)
gemm256(const bfu* __restrict__ A, const bfu* __restrict__ Bt,
        void* __restrict__ Cv, int N, int K) {
    __shared__ __align__(16) char lds[131072];
    const int tid  = threadIdx.x;
    const int lane = tid & 63;
    const int wid  = tid >> 6;
    const int wm   = wid >> 2, wn = wid & 3;
    const int nwg  = gridDim.x * gridDim.y;
    const int flat = blockIdx.y * gridDim.x + blockIdx.x;
    const int swz  = (flat & 7) * (nwg >> 3) + (flat >> 3);
    const long m0 = (long)(swz / gridDim.x) * 256;
    const long n0 = (long)(swz % gridDim.x) * 256;

    // ---- staging descriptors: per half-tile, thread covers 2x16B chunks ----
    int rowj[2], ssj[2], dstj[2];
#pragma unroll
    for (int j = 0; j < 2; ++j) {
        int idx = j * 512 + tid;
        rowj[j] = idx >> 3;              // 0..127 within half
        ssj[j]  = (idx & 7) ^ (rowj[j] & 7);
        dstj[j] = idx * 16;
    }
    const long Kl = K;
    const bfu* aS[2]; const bfu* bS[2];
#pragma unroll
    for (int j = 0; j < 2; ++j) {
        aS[j] = A  + (m0 + rowj[j]) * Kl + ssj[j] * 8;
        bS[j] = Bt + (n0 + rowj[j]) * Kl + ssj[j] * 8;
    }
    const long hstep = 128 * Kl;         // advance to half-1 rows

    f32x4 acc[8][4] = {};
    const int NT = K >> 6;

    // ---- prologue: full K-tile 0 -> buf 0 ----
#pragma unroll
    for (int h = 0; h < 2; ++h)
#pragma unroll
        for (int j = 0; j < 2; ++j) {
            __builtin_amdgcn_global_load_lds((GV*)(aS[j] + h * hstep),
                (LV*)(lds + h * 16384 + dstj[j]), 16, 0, 0);
            __builtin_amdgcn_global_load_lds((GV*)(bS[j] + h * hstep),
                (LV*)(lds + 65536 + h * 16384 + dstj[j]), 16, 0, 0);
        }
    asm volatile("s_waitcnt vmcnt(0)" ::: "memory");
    __builtin_amdgcn_s_barrier();

    // ---- read-base offsets: XOR key reduces to lane&7 (frag rows = 0 mod 16) ----
    const int k0s = (lane >> 4) ^ (lane & 7);
    const int k1s = k0s ^ 4;
    const int aro = wm * 16384 + (lane & 15) * 128;
    const int bro = (wn >> 1) * 16384 + ((wn & 1) * 64 + (lane & 15)) * 128;

    for (int kt = 0; kt < NT; ++kt) {
        const int cur = kt & 1;
        const char* Ab = lds + cur * 32768;
        const char* Bb = lds + 65536 + cur * 32768;
        char* An = lds + (cur ^ 1) * 32768;
        char* Bn = lds + 65536 + (cur ^ 1) * 32768;
        const long knext = (long)(kt + 1) << 6;
        const bool more = (kt + 1) < NT;

        const char* a0 = Ab + aro + k0s * 16;
        const char* a1 = Ab + aro + k1s * 16;
        const char* b0 = Bb + bro + k0s * 16;
        const char* b1 = Bb + bro + k1s * 16;

        bf16x8 av[4][2], bv[4][2];

        // phase 0: stage A-half0(kt+1); read av(m0-3)+bv(n0-1); mfma q00
        if (more) {
#pragma unroll
            for (int j = 0; j < 2; ++j)
                __builtin_amdgcn_global_load_lds((GV*)(aS[j] + knext), (LV*)(An + dstj[j]), 16, 0, 0);
        }
#pragma unroll
        for (int mi = 0; mi < 4; ++mi) {
            av[mi][0] = *(const bf16x8*)(a0 + mi * 2048);
            av[mi][1] = *(const bf16x8*)(a1 + mi * 2048);
        }
#pragma unroll
        for (int ni = 0; ni < 2; ++ni) {
            bv[ni][0] = *(const bf16x8*)(b0 + ni * 2048);
            bv[ni][1] = *(const bf16x8*)(b1 + ni * 2048);
        }
#pragma unroll
        for (int mi = 0; mi < 4; ++mi)
#pragma unroll
            for (int ni = 0; ni < 2; ++ni)
#pragma unroll
                for (int kk = 0; kk < 2; ++kk)
                    acc[mi][ni] = __builtin_amdgcn_mfma_f32_16x16x32_bf16(av[mi][kk], bv[ni][kk], acc[mi][ni], 0, 0, 0);

        // phase 1: stage A-half1; read bv(n2-3); mfma q01
        if (more) {
#pragma unroll
            for (int j = 0; j < 2; ++j)
                __builtin_amdgcn_global_load_lds((GV*)(aS[j] + hstep + knext), (LV*)(An + 16384 + dstj[j]), 16, 0, 0);
        }
#pragma unroll
        for (int ni = 0; ni < 2; ++ni) {
            bv[2 + ni][0] = *(const bf16x8*)(b0 + (2 + ni) * 2048);
            bv[2 + ni][1] = *(const bf16x8*)(b1 + (2 + ni) * 2048);
        }
#pragma unroll
        for (int mi = 0; mi < 4; ++mi)
#pragma unroll
            for (int ni = 0; ni < 2; ++ni)
#pragma unroll
                for (int kk = 0; kk < 2; ++kk)
                    acc[mi][2 + ni] = __builtin_amdgcn_mfma_f32_16x16x32_bf16(av[mi][kk], bv[2 + ni][kk], acc[mi][2 + ni], 0, 0, 0);

        // phase 2: stage B-half0; read av(m4-7); mfma q10
        if (more) {
#pragma unroll
            for (int j = 0; j < 2; ++j)
                __builtin_amdgcn_global_load_lds((GV*)(bS[j] + knext), (LV*)(Bn + dstj[j]), 16, 0, 0);
        }
#pragma unroll
        for (int mi = 0; mi < 4; ++mi) {
            av[mi][0] = *(const bf16x8*)(a0 + (4 + mi) * 2048);
            av[mi][1] = *(const bf16x8*)(a1 + (4 + mi) * 2048);
        }
#pragma unroll
        for (int mi = 0; mi < 4; ++mi)
#pragma unroll
            for (int ni = 0; ni < 2; ++ni)
#pragma unroll
                for (int kk = 0; kk < 2; ++kk)
                    acc[4 + mi][ni] = __builtin_amdgcn_mfma_f32_16x16x32_bf16(av[mi][kk], bv[ni][kk], acc[4 + mi][ni], 0, 0, 0);

        // phase 3: stage B-half1; mfma q11
        if (more) {
#pragma unroll
            for (int j = 0; j < 2; ++j)
                __builtin_amdgcn_global_load_lds((GV*)(bS[j] + hstep + knext), (LV*)(Bn + 16384 + dstj[j]), 16, 0, 0);
        }
#pragma unroll
        for (int mi = 0; mi < 4; ++mi)
#pragma unroll
            for (int ni = 0; ni < 2; ++ni)
#pragma unroll
                for (int kk = 0; kk < 2; ++kk)
                    acc[4 + mi][2 + ni] = __builtin_amdgcn_mfma_f32_16x16x32_bf16(av[mi][kk], bv[2 + ni][kk], acc[4 + mi][2 + ni], 0, 0, 0);

        if (more) {
            asm volatile("s_waitcnt vmcnt(0)" ::: "memory");   // own kt+1 loads landed
            __builtin_amdgcn_s_barrier();                      // all waves: tile ready + done reading cur
        }
    }

    // ---- epilogue ----
    const int cr = (lane >> 4) << 2;
    const int cc = lane & 15;
#pragma unroll
    for (int m = 0; m < 8; ++m)
#pragma unroll
        for (int n = 0; n < 4; ++n)
#pragma unroll
            for (int r = 0; r < 4; ++r) {
                long row = m0 + wm * 128 + m * 16 + cr + r;
                long col = n0 + wn * 64 + n * 16 + cc;
                float val = acc[m][n][r];
                if (MODE == 1) {
                    ((float*)Cv)[row * N + col] = val;
                } else {                  // q-proj -> qr rope-layout
                    long b_ = row >> 11;
                    long s  = row & 2047;
                    unsigned int h = (unsigned int)col / 192u;
                    unsigned int d = (unsigned int)col - h * 192u;
                    ((bfu*)Cv)[((b_ * HH + h) * SS + s) * (long)QKD + d] = (bfu)f2bf(val);
                }
            }
}

// ---------------- merged: in-place RoPE on qr pe-cols + kall pe fill ----------------
__global__ void rope_pe_fill(bfu* __restrict__ qr, const bfu* __restrict__ kpe,
                             bfu* __restrict__ kall,
                             const float* __restrict__ fc, const float* __restrict__ fs) {
    long t = (long)blockIdx.x * 256 + threadIdx.x;
    int  ch = (int)(t & 7);
    long r  = t >> 3;
    int  s  = (int)(r & 2047);
    long bh = (r >> 11) & 63;
    long b_ = bh >> 4;
    if (t < 1048576L) {
        bfu* p = qr + (bh * SS + s) * (long)QKD + NOPE + ch * 8;
        bf16x8 v = *(const bf16x8*)p;
        int i0 = ch * 4;
        unsigned int out[4];
#pragma unroll
        for (int k = 0; k < 4; ++k) {
            float e = bf2f((unsigned short)v[2 * k]);
            float o = bf2f((unsigned short)v[2 * k + 1]);
            float c = fc[s * 32 + i0 + k], sn = fs[s * 32 + i0 + k];
            out[k] = cvt_pk_bf16(e * c - o * sn, e * sn + o * c);
        }
        *(uint4*)p = make_uint4(out[0], out[1], out[2], out[3]);
    } else {
        bf16x8 v = *(const bf16x8*)(kpe + (b_ * SS + s) * (long)ROPE + ch * 8);
        *(bf16x8*)(kall + (bh * SS + s) * (long)QKD + NOPE + ch * 8) = v;
    }
}

// ---------------- RMSNorm(kv_c) + RoPE(k_pe), one block per (b,s) row ----------------
__global__ void __launch_bounds__(256)
rms_rope_kv(const bfu* __restrict__ kv1, const float* __restrict__ wn,
            bfu* __restrict__ kvc, bfu* __restrict__ kpe,
            const float* __restrict__ fc, const float* __restrict__ fs) {
    const int row = blockIdx.x;            // b*S + s
    const int t   = threadIdx.x;
    const int s   = row & (SS - 1);
    const long base = (long)row * 640;
    unsigned int v = *(const unsigned int*)(kv1 + base + 2 * t);
    float a = bf2f(v & 0xffff), c2 = bf2f(v >> 16);
    float ssum = a * a + c2 * c2;
#pragma unroll
    for (int d = 1; d < 64; d <<= 1) ssum += __shfl_xor(ssum, d);
    __shared__ float red[4];
    const int lane = t & 63, w = t >> 6;
    if (lane == 0) red[w] = ssum;
    __syncthreads();
    float tot = red[0] + red[1] + red[2] + red[3];
    float scale = rsqrtf(tot * (1.0f / 512.0f) + 1e-6f);
    float w0 = wn[2 * t], w1 = wn[2 * t + 1];
    unsigned int out = f2bf(a * scale * w0) | (f2bf(c2 * scale * w1) << 16);
    *(unsigned int*)(kvc + (long)row * KVR + 2 * t) = out;
    if (t < 32) {
        unsigned int pv = *(const unsigned int*)(kv1 + base + KVR + 2 * t);
        float e = bf2f(pv & 0xffff), o = bf2f(pv >> 16);
        float cc = fc[s * 32 + t], sn = fs[s * 32 + t];
        unsigned int po = f2bf(e * cc - o * sn) | (f2bf(e * sn + o * cc) << 16);
        *(unsigned int*)(kpe + (long)row * ROPE + 2 * t) = po;
    }
}

// ---------------- flash causal attention (R13/R15 best) ----------------
template <bool MASKED>
__device__ __forceinline__ void attn_tile64(
    const char* kbuf, const char* vbuf, char* pw,
    const bf16x8 (&qf)[6], f32x4 (&accv)[8],
    float& ms, float& ls, int kv0, int qa, int ql, int kg, int lane) {
    // ---- QK^T from LDS: C[kv][q] ----
    f32x4 sc[4] = {};
#pragma unroll
    for (int j = 0; j < 4; ++j)
#pragma unroll
        for (int d = 0; d < 6; ++d) {
            int row  = j * 16 + ql;
            int slot = (d * 4 + kg) ^ (ql & 7);
            bf16x8 kf = *(const bf16x8*)(kbuf + row * 384 + slot * 16);
            sc[j] = __builtin_amdgcn_mfma_f32_16x16x32_bf16(kf, qf[d], sc[j], 0, 0, 0);
        }
    // ---- online softmax ----
    float p[4][4];
    float mx = -1e30f;
#pragma unroll
    for (int j = 0; j < 4; ++j)
#pragma unroll
        for (int r = 0; r < 4; ++r) {
            float s = sc[j][r];
            if (MASKED) {
                int kv = kv0 + j * 16 + kg * 4 + r;
                s = (kv > qa) ? -1e30f : s;
            }
            p[j][r] = s;
            mx = fmaxf(mx, s);
        }
    mx = fmaxf(mx, __shfl_xor(mx, 16));
    mx = fmaxf(mx, __shfl_xor(mx, 32));
    float rs = 0.f;
    if (__all(mx <= ms)) {            // defer-max
#pragma unroll
        for (int j = 0; j < 4; ++j)
#pragma unroll
            for (int r = 0; r < 4; ++r) {
                float e = exp2f(p[j][r] - ms);
                p[j][r] = e;
                rs += e;
            }
        rs += __shfl_xor(rs, 16);
        rs += __shfl_xor(rs, 32);
        ls += rs;
    } else {
        float mn = fmaxf(ms, mx);
        float al = exp2f(ms - mn);
        ms = mn;
#pragma unroll
        for (int j = 0; j < 4; ++j)
#pragma unroll
            for (int r = 0; r < 4; ++r) {
                float e = exp2f(p[j][r] - mn);
                p[j][r] = e;
                rs += e;
            }
        rs += __shfl_xor(rs, 16);
        rs += __shfl_xor(rs, 32);
        ls = ls * al + rs;
        float alT[4];
#pragma unroll
        for (int r = 0; r < 4; ++r)
            alT[r] = __shfl(al, (lane & 48) + kg * 4 + r);
#pragma unroll
        for (int v8 = 0; v8 < 8; ++v8)
#pragma unroll
            for (int r = 0; r < 4; ++r)
                accv[v8][r] *= alT[r];
    }
    // ---- repack P -> wave LDS, cvt_pk ----
#pragma unroll
    for (int j = 0; j < 4; ++j) {
        uint2 u;
        u.x = cvt_pk_bf16(p[j][0], p[j][1]);
        u.y = cvt_pk_bf16(p[j][2], p[j][3]);
        int slot = (2 * j + (kg >> 1)) ^ (ql & 7);
        *(uint2*)(pw + ql * 128 + slot * 16 + (kg & 1) * 8) = u;
    }
    asm volatile("s_waitcnt lgkmcnt(0)" ::: "memory");
    // ---- PV from LDS ----
#pragma unroll
    for (int t2 = 0; t2 < 2; ++t2) {
        int ps = (t2 * 4 + kg) ^ (ql & 7);
        bf16x8 pa = *(const bf16x8*)(pw + ql * 128 + ps * 16);
#pragma unroll
        for (int v8 = 0; v8 < 8; ++v8) {
            int vrow = v8 * 16 + ql;
            int vs   = (t2 * 4 + kg) ^ (ql & 7);
            bf16x8 vf = *(const bf16x8*)(vbuf + vrow * 128 + vs * 16);
            accv[v8] = __builtin_amdgcn_mfma_f32_16x16x32_bf16(pa, vf, accv[v8], 0, 0, 0);
        }
    }
}

__global__ void __launch_bounds__(512)
attn(const bfu* __restrict__ qr, const bfu* __restrict__ kall,
     const bfu* __restrict__ vt, bfu* __restrict__ ao) {
    __shared__ __align__(16) char kbuf[2][64 * 384];   // 2 x 24576
    __shared__ __align__(16) char vbuf[2][128 * 128];  // 2 x 16384
    __shared__ __align__(16) char pbuf[8][2048];       // 16384 -> 98304 total
    const int tid  = threadIdx.x;
    const int lane = tid & 63;
    const int w    = tid >> 6;           // 0..7
    const int ql   = lane & 15;
    const int kg   = lane >> 4;
    const int bid  = blockIdx.x;
    const int qb   = 15 - (bid >> 6);    // longest blocks first
    const int bh   = bid & 63;
    const int h    = bh & 15;
    const int b    = bh >> 4;
    const char* Q  = (const char*)(qr + (long)bh * SS * QKD);
    const char* Kp = (const char*)(kall + (long)bh * SS * QKD);
    const char* Vp = (const char*)(vt + (long)bh * VD * SS);
    char* pw = pbuf[w];

    const int qa_min = qb * 128 + w * 16;
    const int qa = qa_min + ql;

    const char* ksrc[3]; int kdst[3];
#pragma unroll
    for (int i = 0; i < 3; ++i) {
        int idx  = i * 512 + tid;
        int row  = idx / 24;
        int slot = idx - row * 24;
        int ss   = slot ^ (row & 7);
        ksrc[i]  = Kp + (long)row * 384 + ss * 16;
        kdst[i]  = idx * 16;
    }
    const char* vsrc[2]; int vdst[2];
#pragma unroll
    for (int i = 0; i < 2; ++i) {
        int idx  = i * 512 + tid;
        int row  = idx >> 3;
        int slot = idx & 7;
        int ss   = slot ^ (row & 7);
        vsrc[i]  = Vp + (long)row * (SS * 2) + ss * 16;
        vdst[i]  = idx * 16;
    }
    auto stage = [&](int bi, int kv0) {
        const long ko = (long)kv0 * 384;
        const long vo = (long)kv0 * 2;
#pragma unroll
        for (int i = 0; i < 3; ++i)
            __builtin_amdgcn_global_load_lds((GV*)(ksrc[i] + ko), (LV*)(kbuf[bi] + kdst[i]), 16, 0, 0);
#pragma unroll
        for (int i = 0; i < 2; ++i)
            __builtin_amdgcn_global_load_lds((GV*)(vsrc[i] + vo), (LV*)(vbuf[bi] + vdst[i]), 16, 0, 0);
    };

    bf16x8 qf[6];
#pragma unroll
    for (int d = 0; d < 6; ++d)
        qf[d] = *(const bf16x8*)(Q + (long)(qa_min + ql) * 384 + d * 64 + kg * 16);

    f32x4 accv[8] = {};
    float ms = -1e30f, ls = 0.f;
    const int ntiles = 2 * qb + 2;

    stage(0, 0);                         // prologue prefetch
    __syncthreads();                     // drains vmcnt(0): buf0 ready

    for (int t = 0; t < ntiles; ++t) {
        const int cur = t & 1;
        const int kv0 = t * 64;
        if (t + 1 < ntiles)
            stage(cur ^ 1, kv0 + 64);    // issue next tile; latency hides under compute
        if (kv0 + 63 <= qa_min)
            attn_tile64<false>(kbuf[cur], vbuf[cur], pw, qf, accv, ms, ls, kv0, qa, ql, kg, lane);
        else if (kv0 <= qa_min + 15)
            attn_tile64<true>(kbuf[cur], vbuf[cur], pw, qf, accv, ms, ls, kv0, qa, ql, kg, lane);
        asm volatile("s_waitcnt vmcnt(0)" ::: "memory");
        __builtin_amdgcn_s_barrier();
        asm volatile("" ::: "memory");
    }
    float li[4];
#pragma unroll
    for (int r = 0; r < 4; ++r)
        li[r] = 1.0f / __shfl(ls, (lane & 48) + kg * 4 + r);
#pragma unroll
    for (int v8 = 0; v8 < 8; ++v8)
#pragma unroll
        for (int r = 0; r < 4; ++r) {
            float o = accv[v8][r] * li[r];
            long row = (long)b * SS + qa_min + kg * 4 + r;
            ao[row * (long)(HH * VD) + h * VD + v8 * 16 + ql] = (bfu)f2bf(o);
        }
}

// ---------------- workspace layout (bytes) ----------------
#define O_XB   0L                     // x bf16 33,554,432      (later: vt alias)
#define O_WQ   33554432L              // wq bf16 12,582,912 (scaled by SCL2)
#define O_WA   46137344L              // wkv_a padded 2,621,440
#define O_WKB  48758784L              // wkv_b K-part [2048][512] 2,097,152
#define O_WVB  50855936L              // wkv_b V-part [2048][512] 2,097,152
#define O_WO   52953088L              // wo 8,388,608
#define O_KALL 61341696L              // K assembled 50,331,648
#define O_KV1  111673344L             // kv_a compact out 8192x640 bf16 = 10,485,760
#define O_QR   122159104L             // q rope-layout 50,331,648 (written by q-proj)
#define O_KVC  172490752L             // kv_c 8,388,608
#define O_KPE  180879360L             // k_pe 1,048,576
#define O_AO   181927936L             // attn out 33,554,432
#define WS_NEED 215482368L

extern "C" void kernel_launch(void* const* d_in, const int* in_sizes, int n_in,
                              void* d_out, int out_size, void* d_ws, size_t ws_size,
                              hipStream_t stream) {
    const float* x      = (const float*)d_in[0];
    const float* wq     = (const float*)d_in[1];
    const float* wkv_a  = (const float*)d_in[2];
    const float* kvnw   = (const float*)d_in[3];
    const float* wkv_b  = (const float*)d_in[4];
    const float* wo     = (const float*)d_in[5];
    const float* fcos   = (const float*)d_in[6];
    const float* fsin   = (const float*)d_in[7];
    if (ws_size < (size_t)WS_NEED) return;

    char* ws = (char*)d_ws;
    bfu* xb   = (bfu*)(ws + O_XB);
    bfu* wqb  = (bfu*)(ws + O_WQ);
    bfu* wab  = (bfu*)(ws + O_WA);
    bfu* wkb  = (bfu*)(ws + O_WKB);
    bfu* wvb  = (bfu*)(ws + O_WVB);
    bfu* wob  = (bfu*)(ws + O_WO);
    bfu* kall = (bfu*)(ws + O_KALL);
    bfu* kv1  = (bfu*)(ws + O_KV1);
    bfu* qr   = (bfu*)(ws + O_QR);
    bfu* kvc  = (bfu*)(ws + O_KVC);
    bfu* kpe  = (bfu*)(ws + O_KPE);
    bfu* ao   = (bfu*)(ws + O_AO);
    bfu* vt   = xb;                   // alias (xb dead after projections)

    // 1. all casts in one dispatch
    cast_all<<<29952, 256, 0, stream>>>(x, wq, wkv_a, wkv_b, wo,
                                        xb, wqb, wab, wkb, wvb, wob);

    // 2. q-proj (256-tile pipelined) -> qr rope-layout
    gemm256<0><<<dim3(12, 32), 512, 0, stream>>>(xb, wqb, qr, 3072, DD);

    // 3. kv_a proj (128-tile) -> compact kv1 [8192][640]
    gemm_bt<0><<<dim3(5, 64), 256, 0, stream>>>(xb, wab, kv1, nullptr, 640, DD);

    // 4. rmsnorm + k_pe rope
    rms_rope_kv<<<ROWS, 256, 0, stream>>>(kv1, kvnw, kvc, kpe, fcos, fsin);

    // 5. kv_b K-part -> kall ; V^T -> vt
    gemm_bt<2><<<dim3(16, 64), 256, 0, stream>>>(kvc, wkb, nullptr, kall, 2048, KVR);
    gemm_bt<4><<<dim3(64, 16), 256, 0, stream>>>(wvb, kvc, vt, nullptr, 8192, KVR);

    // 6. in-place q-pe rope + kall pe fill
    rope_pe_fill<<<8192, 256, 0, stream>>>(qr, kpe, kall, fcos, fsin);

    // 7. attention
    attn<<<1024, 512, 0, stream>>>(qr, kall, vt, ao);

    // 8. output projection (256-tile pipelined, fp32 out)
    gemm256<1><<<dim3(8, 32), 512, 0, stream>>>(ao, wob, d_out, 2048, HH * VD);
}

// Round 17
// 465.997 us; speedup vs baseline: 1.1012x; 1.0147x over previous
//
#include <hip/hip_runtime.h>
#include <math.h>

// ---------------- problem constants ----------------
#define BB 4
#define SS 2048
#define DD 2048
#define HH 16
#define NOPE 128
#define ROPE 64
#define VD 128
#define QKD 192         // NOPE+ROPE
#define KVR 512
#define ROWS (BB*SS)    // 8192
// log2(e) / sqrt(192), folded into wq at cast time
#define SCL2 0.1041216338380858f

typedef __attribute__((ext_vector_type(8))) short bf16x8;
typedef __attribute__((ext_vector_type(4))) float f32x4;
typedef unsigned short bfu;
typedef __attribute__((address_space(1))) const void GV;
typedef __attribute__((address_space(3))) void LV;

__device__ __forceinline__ float bf2f(unsigned int u) {
    unsigned int i = u << 16; float f; __builtin_memcpy(&f, &i, 4); return f;
}
__device__ __forceinline__ unsigned int f2bf(float f) {
    unsigned int i; __builtin_memcpy(&i, &f, 4);
    return (i + 0x7fffu + ((i >> 16) & 1u)) >> 16;
}
__device__ __forceinline__ unsigned int cvt_pk_bf16(float lo, float hi) {
    unsigned int r;
    asm("v_cvt_pk_bf16_f32 %0, %1, %2" : "=v"(r) : "v"(lo), "v"(hi));
    return r;
}

// ---------------- one fused cast: x | wq*SCL2 | wkv_a(+pad) | wkv_b(->wkb/wvb) | wo ----------------
__global__ void cast_all(const float* __restrict__ x, const float* __restrict__ wq,
                         const float* __restrict__ wa, const float* __restrict__ wb,
                         const float* __restrict__ wo,
                         bfu* __restrict__ dx, bfu* __restrict__ dq,
                         bfu* __restrict__ da, bfu* __restrict__ dkb,
                         bfu* __restrict__ dvb, bfu* __restrict__ dwo) {
    long i = (long)blockIdx.x * 256 + threadIdx.x;   // one float4 each
    const float* src; bfu* dst; long off, n_src; float scl = 1.0f;
    if (i < 4194304L)        { src = x;  dst = dx;  off = i;            n_src = 4194304L; }
    else if (i < 5767168L)   { src = wq; dst = dq;  off = i - 4194304L; n_src = 1572864L; scl = SCL2; }
    else if (i < 6094848L)   { src = wa; dst = da;  off = i - 5767168L; n_src = 294912L;  }
    else if (i < 6619136L)   {          // wkv_b: split K-rows / V-rows
        long off2 = i - 6094848L;       // float4 index into wkv_b [4096][128]
        long row = off2 >> 7, c = off2 & 127;
        long h = row >> 8, wi = row & 255;
        bfu* d2 = (wi < 128) ? dkb : dvb;
        long drow = (h << 7) + (wi & 127);
        float4 v = ((const float4*)wb)[off2];
        unsigned int lo = f2bf(v.x) | (f2bf(v.y) << 16);
        unsigned int hi = f2bf(v.z) | (f2bf(v.w) << 16);
        ((uint2*)d2)[drow * 128 + c] = make_uint2(lo, hi);
        return;
    }
    else if (i < 7667712L)   { src = wo; dst = dwo; off = i - 6619136L; n_src = 1048576L; }
    else return;
    unsigned int lo = 0, hi = 0;
    if (off < n_src) {
        float4 v = ((const float4*)src)[off];
        lo = f2bf(v.x * scl) | (f2bf(v.y * scl) << 16);
        hi = f2bf(v.z * scl) | (f2bf(v.w * scl) << 16);
    }
    ((uint2*)dst)[off] = make_uint2(lo, hi);
}

// ---------------- 128x128 tile bf16 GEMM (proven m97 structure) ----------------
// MODE 0: bf16 linear out.
template <int MODE>
__global__ void __launch_bounds__(256)
gemm_bt(const bfu* __restrict__ A, const bfu* __restrict__ Bt,
        void* __restrict__ Cv, bfu* __restrict__ C2, int N, int K) {
    __shared__ __align__(16) char lds[32768];
    char* AsB = lds;
    char* BsB = lds + 16384;
    const int tid  = threadIdx.x;
    const int lane = tid & 63;
    const int wid  = tid >> 6;
    const int wr   = wid >> 1, wc = wid & 1;
    const int nwg  = gridDim.x * gridDim.y;
    const int flat = blockIdx.y * gridDim.x + blockIdx.x;
    const int swz  = (flat & 7) * (nwg >> 3) + (flat >> 3);
    const long m0 = (long)(swz / gridDim.x) * 128;
    const long n0 = (long)(swz % gridDim.x) * 128;

    f32x4 acc[4][4] = {};

    const int lr = lane >> 3;            // row within 8-row stripe
    const int SB = (lane & 7) << 4;      // 16B slot within 128B row

    for (int k0 = 0; k0 < K; k0 += 64) {
        __syncthreads();
#pragma unroll
        for (int i = 0; i < 4; ++i) {
            int rb = wid * 32 + i * 8;   // wave-uniform row base
            int R  = rb + lr;
            int c  = (SB ^ ((R & 7) << 4)) >> 1;   // pre-swizzled source column
            const bfu* gA = A  + (m0 + R) * (long)K + k0 + c;
            const bfu* gB = Bt + (n0 + R) * (long)K + k0 + c;
            __builtin_amdgcn_global_load_lds((GV*)gA, (LV*)(AsB + rb * 128), 16, 0, 0);
            __builtin_amdgcn_global_load_lds((GV*)gB, (LV*)(BsB + rb * 128), 16, 0, 0);
        }
        __syncthreads();
#pragma unroll
        for (int kk = 0; kk < 2; ++kk) {
            bf16x8 av[4], bv[4];
            const int cb = kk * 64 + ((lane >> 4) << 4);
#pragma unroll
            for (int m = 0; m < 4; ++m) {
                int R = wr * 64 + m * 16 + (lane & 15);
                av[m] = *(const bf16x8*)(AsB + R * 128 + (cb ^ ((R & 7) << 4)));
            }
#pragma unroll
            for (int n = 0; n < 4; ++n) {
                int R = wc * 64 + n * 16 + (lane & 15);
                bv[n] = *(const bf16x8*)(BsB + R * 128 + (cb ^ ((R & 7) << 4)));
            }
#pragma unroll
            for (int m = 0; m < 4; ++m)
#pragma unroll
                for (int n = 0; n < 4; ++n)
                    acc[m][n] = __builtin_amdgcn_mfma_f32_16x16x32_bf16(av[m], bv[n], acc[m][n], 0, 0, 0);
        }
    }

    const int cr = (lane >> 4) << 2;
    const int cc = lane & 15;
#pragma unroll
    for (int m = 0; m < 4; ++m)
#pragma unroll
        for (int n = 0; n < 4; ++n)
#pragma unroll
            for (int r = 0; r < 4; ++r) {
                long row = m0 + wr * 64 + m * 16 + cr + r;
                long col = n0 + wc * 64 + n * 16 + cc;
                float val = acc[m][n][r];
                if (MODE == 0) {
                    ((bfu*)Cv)[row * N + col] = (bfu)f2bf(val);
                }
            }
}

// ---------------- 256x256 tile bf16 GEMM, 8 waves, 4-phase dbuf pipeline ----------------
// MODE 0: q-proj -> qr rope-layout (col=h*192+d). MODE 1: f32 linear out.
// MODE 2 (kv_b K-part, N=2048): col=h*128+d -> kall scatter (C2 unused, Cv=kall).
// MODE 4 (V^T, M=2048, N=8192): row=h*128+v, col=b*2048+s -> vt[b][h][v][s].
template <int MODE>
__global__ void __launch_bounds__(512)
gemm256(const bfu* __restrict__ A, const bfu* __restrict__ Bt,
        void* __restrict__ Cv, int N, int K) {
    __shared__ __align__(16) char lds[131072];
    const int tid  = threadIdx.x;
    const int lane = tid & 63;
    const int wid  = tid >> 6;
    const int wm   = wid >> 2, wn = wid & 3;
    const int nwg  = gridDim.x * gridDim.y;
    const int flat = blockIdx.y * gridDim.x + blockIdx.x;
    const int swz  = (flat & 7) * (nwg >> 3) + (flat >> 3);
    const long m0 = (long)(swz / gridDim.x) * 256;
    const long n0 = (long)(swz % gridDim.x) * 256;

    // ---- staging descriptors: per half-tile, thread covers 2x16B chunks ----
    int rowj[2], ssj[2], dstj[2];
#pragma unroll
    for (int j = 0; j < 2; ++j) {
        int idx = j * 512 + tid;
        rowj[j] = idx >> 3;              // 0..127 within half
        ssj[j]  = (idx & 7) ^ (rowj[j] & 7);
        dstj[j] = idx * 16;
    }
    const long Kl = K;
    const bfu* aS[2]; const bfu* bS[2];
#pragma unroll
    for (int j = 0; j < 2; ++j) {
        aS[j] = A  + (m0 + rowj[j]) * Kl + ssj[j] * 8;
        bS[j] = Bt + (n0 + rowj[j]) * Kl + ssj[j] * 8;
    }
    const long hstep = 128 * Kl;         // advance to half-1 rows

    f32x4 acc[8][4] = {};
    const int NT = K >> 6;

    // ---- prologue: full K-tile 0 -> buf 0 ----
#pragma unroll
    for (int h = 0; h < 2; ++h)
#pragma unroll
        for (int j = 0; j < 2; ++j) {
            __builtin_amdgcn_global_load_lds((GV*)(aS[j] + h * hstep),
                (LV*)(lds + h * 16384 + dstj[j]), 16, 0, 0);
            __builtin_amdgcn_global_load_lds((GV*)(bS[j] + h * hstep),
                (LV*)(lds + 65536 + h * 16384 + dstj[j]), 16, 0, 0);
        }
    asm volatile("s_waitcnt vmcnt(0)" ::: "memory");
    __builtin_amdgcn_s_barrier();

    // ---- read-base offsets: XOR key reduces to lane&7 (frag rows = 0 mod 16) ----
    const int k0s = (lane >> 4) ^ (lane & 7);
    const int k1s = k0s ^ 4;
    const int aro = wm * 16384 + (lane & 15) * 128;
    const int bro = (wn >> 1) * 16384 + ((wn & 1) * 64 + (lane & 15)) * 128;

    for (int kt = 0; kt < NT; ++kt) {
        const int cur = kt & 1;
        const char* Ab = lds + cur * 32768;
        const char* Bb = lds + 65536 + cur * 32768;
        char* An = lds + (cur ^ 1) * 32768;
        char* Bn = lds + 65536 + (cur ^ 1) * 32768;
        const long knext = (long)(kt + 1) << 6;
        const bool more = (kt + 1) < NT;

        const char* a0 = Ab + aro + k0s * 16;
        const char* a1 = Ab + aro + k1s * 16;
        const char* b0 = Bb + bro + k0s * 16;
        const char* b1 = Bb + bro + k1s * 16;

        bf16x8 av[4][2], bv[4][2];

        // phase 0: stage A-half0(kt+1); read av(m0-3)+bv(n0-1); mfma q00
        if (more) {
#pragma unroll
            for (int j = 0; j < 2; ++j)
                __builtin_amdgcn_global_load_lds((GV*)(aS[j] + knext), (LV*)(An + dstj[j]), 16, 0, 0);
        }
#pragma unroll
        for (int mi = 0; mi < 4; ++mi) {
            av[mi][0] = *(const bf16x8*)(a0 + mi * 2048);
            av[mi][1] = *(const bf16x8*)(a1 + mi * 2048);
        }
#pragma unroll
        for (int ni = 0; ni < 2; ++ni) {
            bv[ni][0] = *(const bf16x8*)(b0 + ni * 2048);
            bv[ni][1] = *(const bf16x8*)(b1 + ni * 2048);
        }
#pragma unroll
        for (int mi = 0; mi < 4; ++mi)
#pragma unroll
            for (int ni = 0; ni < 2; ++ni)
#pragma unroll
                for (int kk = 0; kk < 2; ++kk)
                    acc[mi][ni] = __builtin_amdgcn_mfma_f32_16x16x32_bf16(av[mi][kk], bv[ni][kk], acc[mi][ni], 0, 0, 0);

        // phase 1: stage A-half1; read bv(n2-3); mfma q01
        if (more) {
#pragma unroll
            for (int j = 0; j < 2; ++j)
                __builtin_amdgcn_global_load_lds((GV*)(aS[j] + hstep + knext), (LV*)(An + 16384 + dstj[j]), 16, 0, 0);
        }
#pragma unroll
        for (int ni = 0; ni < 2; ++ni) {
            bv[2 + ni][0] = *(const bf16x8*)(b0 + (2 + ni) * 2048);
            bv[2 + ni][1] = *(const bf16x8*)(b1 + (2 + ni) * 2048);
        }
#pragma unroll
        for (int mi = 0; mi < 4; ++mi)
#pragma unroll
            for (int ni = 0; ni < 2; ++ni)
#pragma unroll
                for (int kk = 0; kk < 2; ++kk)
                    acc[mi][2 + ni] = __builtin_amdgcn_mfma_f32_16x16x32_bf16(av[mi][kk], bv[2 + ni][kk], acc[mi][2 + ni], 0, 0, 0);

        // phase 2: stage B-half0; read av(m4-7); mfma q10
        if (more) {
#pragma unroll
            for (int j = 0; j < 2; ++j)
                __builtin_amdgcn_global_load_lds((GV*)(bS[j] + knext), (LV*)(Bn + dstj[j]), 16, 0, 0);
        }
#pragma unroll
        for (int mi = 0; mi < 4; ++mi) {
            av[mi][0] = *(const bf16x8*)(a0 + (4 + mi) * 2048);
            av[mi][1] = *(const bf16x8*)(a1 + (4 + mi) * 2048);
        }
#pragma unroll
        for (int mi = 0; mi < 4; ++mi)
#pragma unroll
            for (int ni = 0; ni < 2; ++ni)
#pragma unroll
                for (int kk = 0; kk < 2; ++kk)
                    acc[4 + mi][ni] = __builtin_amdgcn_mfma_f32_16x16x32_bf16(av[mi][kk], bv[ni][kk], acc[4 + mi][ni], 0, 0, 0);

        // phase 3: stage B-half1; mfma q11
        if (more) {
#pragma unroll
            for (int j = 0; j < 2; ++j)
                __builtin_amdgcn_global_load_lds((GV*)(bS[j] + hstep + knext), (LV*)(Bn + 16384 + dstj[j]), 16, 0, 0);
        }
#pragma unroll
        for (int mi = 0; mi < 4; ++mi)
#pragma unroll
            for (int ni = 0; ni < 2; ++ni)
#pragma unroll
                for (int kk = 0; kk < 2; ++kk)
                    acc[4 + mi][2 + ni] = __builtin_amdgcn_mfma_f32_16x16x32_bf16(av[mi][kk], bv[2 + ni][kk], acc[4 + mi][2 + ni], 0, 0, 0);

        if (more) {
            asm volatile("s_waitcnt vmcnt(0)" ::: "memory");   // own kt+1 loads landed
            __builtin_amdgcn_s_barrier();                      // all waves: tile ready + done reading cur
        }
    }

    // ---- epilogue ----
    const int cr = (lane >> 4) << 2;
    const int cc = lane & 15;
#pragma unroll
    for (int m = 0; m < 8; ++m)
#pragma unroll
        for (int n = 0; n < 4; ++n)
#pragma unroll
            for (int r = 0; r < 4; ++r) {
                long row = m0 + wm * 128 + m * 16 + cr + r;
                long col = n0 + wn * 64 + n * 16 + cc;
                float val = acc[m][n][r];
                if (MODE == 1) {
                    ((float*)Cv)[row * N + col] = val;
                } else if (MODE == 0) {   // q-proj -> qr rope-layout
                    long b_ = row >> 11;
                    long s  = row & 2047;
                    unsigned int h = (unsigned int)col / 192u;
                    unsigned int d = (unsigned int)col - h * 192u;
                    ((bfu*)Cv)[((b_ * HH + h) * SS + s) * (long)QKD + d] = (bfu)f2bf(val);
                } else if (MODE == 2) {   // kv_b K-part -> kall
                    long b_ = row >> 11;
                    long s  = row & 2047;
                    long h  = col >> 7;
                    long d  = col & 127;
                    ((bfu*)Cv)[((b_ * HH + h) * SS + s) * (long)QKD + d] = (bfu)f2bf(val);
                } else {                  // MODE 4: V^T -> vt[b][h][v][s]
                    long h  = row >> 7;
                    long v  = row & 127;
                    long b_ = col >> 11;
                    long s  = col & 2047;
                    ((bfu*)Cv)[(((b_ * HH + h) * VD) + v) * SS + s] = (bfu)f2bf(val);
                }
            }
}

// ---------------- merged: in-place RoPE on qr pe-cols + kall pe fill ----------------
__global__ void rope_pe_fill(bfu* __restrict__ qr, const bfu* __restrict__ kpe,
                             bfu* __restrict__ kall,
                             const float* __restrict__ fc, const float* __restrict__ fs) {
    long t = (long)blockIdx.x * 256 + threadIdx.x;
    int  ch = (int)(t & 7);
    long r  = t >> 3;
    int  s  = (int)(r & 2047);
    long bh = (r >> 11) & 63;
    long b_ = bh >> 4;
    if (t < 1048576L) {
        bfu* p = qr + (bh * SS + s) * (long)QKD + NOPE + ch * 8;
        bf16x8 v = *(const bf16x8*)p;
        int i0 = ch * 4;
        unsigned int out[4];
#pragma unroll
        for (int k = 0; k < 4; ++k) {
            float e = bf2f((unsigned short)v[2 * k]);
            float o = bf2f((unsigned short)v[2 * k + 1]);
            float c = fc[s * 32 + i0 + k], sn = fs[s * 32 + i0 + k];
            out[k] = cvt_pk_bf16(e * c - o * sn, e * sn + o * c);
        }
        *(uint4*)p = make_uint4(out[0], out[1], out[2], out[3]);
    } else {
        bf16x8 v = *(const bf16x8*)(kpe + (b_ * SS + s) * (long)ROPE + ch * 8);
        *(bf16x8*)(kall + (bh * SS + s) * (long)QKD + NOPE + ch * 8) = v;
    }
}

// ---------------- RMSNorm(kv_c) + RoPE(k_pe), one block per (b,s) row ----------------
__global__ void __launch_bounds__(256)
rms_rope_kv(const bfu* __restrict__ kv1, const float* __restrict__ wn,
            bfu* __restrict__ kvc, bfu* __restrict__ kpe,
            const float* __restrict__ fc, const float* __restrict__ fs) {
    const int row = blockIdx.x;            // b*S + s
    const int t   = threadIdx.x;
    const int s   = row & (SS - 1);
    const long base = (long)row * 640;
    unsigned int v = *(const unsigned int*)(kv1 + base + 2 * t);
    float a = bf2f(v & 0xffff), c2 = bf2f(v >> 16);
    float ssum = a * a + c2 * c2;
#pragma unroll
    for (int d = 1; d < 64; d <<= 1) ssum += __shfl_xor(ssum, d);
    __shared__ float red[4];
    const int lane = t & 63, w = t >> 6;
    if (lane == 0) red[w] = ssum;
    __syncthreads();
    float tot = red[0] + red[1] + red[2] + red[3];
    float scale = rsqrtf(tot * (1.0f / 512.0f) + 1e-6f);
    float w0 = wn[2 * t], w1 = wn[2 * t + 1];
    unsigned int out = f2bf(a * scale * w0) | (f2bf(c2 * scale * w1) << 16);
    *(unsigned int*)(kvc + (long)row * KVR + 2 * t) = out;
    if (t < 32) {
        unsigned int pv = *(const unsigned int*)(kv1 + base + KVR + 2 * t);
        float e = bf2f(pv & 0xffff), o = bf2f(pv >> 16);
        float cc = fc[s * 32 + t], sn = fs[s * 32 + t];
        unsigned int po = f2bf(e * cc - o * sn) | (f2bf(e * sn + o * cc) << 16);
        *(unsigned int*)(kpe + (long)row * ROPE + 2 * t) = po;
    }
}

// ---------------- flash causal attention (R13/R15 best) ----------------
template <bool MASKED>
__device__ __forceinline__ void attn_tile64(
    const char* kbuf, const char* vbuf, char* pw,
    const bf16x8 (&qf)[6], f32x4 (&accv)[8],
    float& ms, float& ls, int kv0, int qa, int ql, int kg, int lane) {
    // ---- QK^T from LDS: C[kv][q] ----
    f32x4 sc[4] = {};
#pragma unroll
    for (int j = 0; j < 4; ++j)
#pragma unroll
        for (int d = 0; d < 6; ++d) {
            int row  = j * 16 + ql;
            int slot = (d * 4 + kg) ^ (ql & 7);
            bf16x8 kf = *(const bf16x8*)(kbuf + row * 384 + slot * 16);
            sc[j] = __builtin_amdgcn_mfma_f32_16x16x32_bf16(kf, qf[d], sc[j], 0, 0, 0);
        }
    // ---- online softmax ----
    float p[4][4];
    float mx = -1e30f;
#pragma unroll
    for (int j = 0; j < 4; ++j)
#pragma unroll
        for (int r = 0; r < 4; ++r) {
            float s = sc[j][r];
            if (MASKED) {
                int kv = kv0 + j * 16 + kg * 4 + r;
                s = (kv > qa) ? -1e30f : s;
            }
            p[j][r] = s;
            mx = fmaxf(mx, s);
        }
    mx = fmaxf(mx, __shfl_xor(mx, 16));
    mx = fmaxf(mx, __shfl_xor(mx, 32));
    float rs = 0.f;
    if (__all(mx <= ms)) {            // defer-max
#pragma unroll
        for (int j = 0; j < 4; ++j)
#pragma unroll
            for (int r = 0; r < 4; ++r) {
                float e = exp2f(p[j][r] - ms);
                p[j][r] = e;
                rs += e;
            }
        rs += __shfl_xor(rs, 16);
        rs += __shfl_xor(rs, 32);
        ls += rs;
    } else {
        float mn = fmaxf(ms, mx);
        float al = exp2f(ms - mn);
        ms = mn;
#pragma unroll
        for (int j = 0; j < 4; ++j)
#pragma unroll
            for (int r = 0; r < 4; ++r) {
                float e = exp2f(p[j][r] - mn);
                p[j][r] = e;
                rs += e;
            }
        rs += __shfl_xor(rs, 16);
        rs += __shfl_xor(rs, 32);
        ls = ls * al + rs;
        float alT[4];
#pragma unroll
        for (int r = 0; r < 4; ++r)
            alT[r] = __shfl(al, (lane & 48) + kg * 4 + r);
#pragma unroll
        for (int v8 = 0; v8 < 8; ++v8)
#pragma unroll
            for (int r = 0; r < 4; ++r)
                accv[v8][r] *= alT[r];
    }
    // ---- repack P -> wave LDS, cvt_pk ----
#pragma unroll
    for (int j = 0; j < 4; ++j) {
        uint2 u;
        u.x = cvt_pk_bf16(p[j][0], p[j][1]);
        u.y = cvt_pk_bf16(p[j][2], p[j][3]);
        int slot = (2 * j + (kg >> 1)) ^ (ql & 7);
        *(uint2*)(pw + ql * 128 + slot * 16 + (kg & 1) * 8) = u;
    }
    asm volatile("s_waitcnt lgkmcnt(0)" ::: "memory");
    // ---- PV from LDS ----
#pragma unroll
    for (int t2 = 0; t2 < 2; ++t2) {
        int ps = (t2 * 4 + kg) ^ (ql & 7);
        bf16x8 pa = *(const bf16x8*)(pw + ql * 128 + ps * 16);
#pragma unroll
        for (int v8 = 0; v8 < 8; ++v8) {
            int vrow = v8 * 16 + ql;
            int vs   = (t2 * 4 + kg) ^ (ql & 7);
            bf16x8 vf = *(const bf16x8*)(vbuf + vrow * 128 + vs * 16);
            accv[v8] = __builtin_amdgcn_mfma_f32_16x16x32_bf16(pa, vf, accv[v8], 0, 0, 0);
        }
    }
}

__global__ void __launch_bounds__(512)
attn(const bfu* __restrict__ qr, const bfu* __restrict__ kall,
     const bfu* __restrict__ vt, bfu* __restrict__ ao) {
    __shared__ __align__(16) char kbuf[2][64 * 384];   // 2 x 24576
    __shared__ __align__(16) char vbuf[2][128 * 128];  // 2 x 16384
    __shared__ __align__(16) char pbuf[8][2048];       // 16384 -> 98304 total
    const int tid  = threadIdx.x;
    const int lane = tid & 63;
    const int w    = tid >> 6;           // 0..7
    const int ql   = lane & 15;
    const int kg   = lane >> 4;
    const int bid  = blockIdx.x;
    const int qb   = 15 - (bid >> 6);    // longest blocks first
    const int bh   = bid & 63;
    const int h    = bh & 15;
    const int b    = bh >> 4;
    const char* Q  = (const char*)(qr + (long)bh * SS * QKD);
    const char* Kp = (const char*)(kall + (long)bh * SS * QKD);
    const char* Vp = (const char*)(vt + (long)bh * VD * SS);
    char* pw = pbuf[w];

    const int qa_min = qb * 128 + w * 16;
    const int qa = qa_min + ql;

    const char* ksrc[3]; int kdst[3];
#pragma unroll
    for (int i = 0; i < 3; ++i) {
        int idx  = i * 512 + tid;
        int row  = idx / 24;
        int slot = idx - row * 24;
        int ss   = slot ^ (row & 7);
        ksrc[i]  = Kp + (long)row * 384 + ss * 16;
        kdst[i]  = idx * 16;
    }
    const char* vsrc[2]; int vdst[2];
#pragma unroll
    for (int i = 0; i < 2; ++i) {
        int idx  = i * 512 + tid;
        int row  = idx >> 3;
        int slot = idx & 7;
        int ss   = slot ^ (row & 7);
        vsrc[i]  = Vp + (long)row * (SS * 2) + ss * 16;
        vdst[i]  = idx * 16;
    }
    auto stage = [&](int bi, int kv0) {
        const long ko = (long)kv0 * 384;
        const long vo = (long)kv0 * 2;
#pragma unroll
        for (int i = 0; i < 3; ++i)
            __builtin_amdgcn_global_load_lds((GV*)(ksrc[i] + ko), (LV*)(kbuf[bi] + kdst[i]), 16, 0, 0);
#pragma unroll
        for (int i = 0; i < 2; ++i)
            __builtin_amdgcn_global_load_lds((GV*)(vsrc[i] + vo), (LV*)(vbuf[bi] + vdst[i]), 16, 0, 0);
    };

    bf16x8 qf[6];
#pragma unroll
    for (int d = 0; d < 6; ++d)
        qf[d] = *(const bf16x8*)(Q + (long)(qa_min + ql) * 384 + d * 64 + kg * 16);

    f32x4 accv[8] = {};
    float ms = -1e30f, ls = 0.f;
    const int ntiles = 2 * qb + 2;

    stage(0, 0);                         // prologue prefetch
    __syncthreads();                     // drains vmcnt(0): buf0 ready

    for (int t = 0; t < ntiles; ++t) {
        const int cur = t & 1;
        const int kv0 = t * 64;
        if (t + 1 < ntiles)
            stage(cur ^ 1, kv0 + 64);    // issue next tile; latency hides under compute
        if (kv0 + 63 <= qa_min)
            attn_tile64<false>(kbuf[cur], vbuf[cur], pw, qf, accv, ms, ls, kv0, qa, ql, kg, lane);
        else if (kv0 <= qa_min + 15)
            attn_tile64<true>(kbuf[cur], vbuf[cur], pw, qf, accv, ms, ls, kv0, qa, ql, kg, lane);
        asm volatile("s_waitcnt vmcnt(0)" ::: "memory");
        __builtin_amdgcn_s_barrier();
        asm volatile("" ::: "memory");
    }
    float li[4];
#pragma unroll
    for (int r = 0; r < 4; ++r)
        li[r] = 1.0f / __shfl(ls, (lane & 48) + kg * 4 + r);
#pragma unroll
    for (int v8 = 0; v8 < 8; ++v8)
#pragma unroll
        for (int r = 0; r < 4; ++r) {
            float o = accv[v8][r] * li[r];
            long row = (long)b * SS + qa_min + kg * 4 + r;
            ao[row * (long)(HH * VD) + h * VD + v8 * 16 + ql] = (bfu)f2bf(o);
        }
}

// ---------------- workspace layout (bytes) ----------------
#define O_XB   0L                     // x bf16 33,554,432      (later: vt alias)
#define O_WQ   33554432L              // wq bf16 12,582,912 (scaled by SCL2)
#define O_WA   46137344L              // wkv_a padded 2,621,440
#define O_WKB  48758784L              // wkv_b K-part [2048][512] 2,097,152
#define O_WVB  50855936L              // wkv_b V-part [2048][512] 2,097,152
#define O_WO   52953088L              // wo 8,388,608
#define O_KALL 61341696L              // K assembled 50,331,648
#define O_KV1  111673344L             // kv_a compact out 8192x640 bf16 = 10,485,760
#define O_QR   122159104L             // q rope-layout 50,331,648 (written by q-proj)
#define O_KVC  172490752L             // kv_c 8,388,608
#define O_KPE  180879360L             // k_pe 1,048,576
#define O_AO   181927936L             // attn out 33,554,432
#define WS_NEED 215482368L

extern "C" void kernel_launch(void* const* d_in, const int* in_sizes, int n_in,
                              void* d_out, int out_size, void* d_ws, size_t ws_size,
                              hipStream_t stream) {
    const float* x      = (const float*)d_in[0];
    const float* wq     = (const float*)d_in[1];
    const float* wkv_a  = (const float*)d_in[2];
    const float* kvnw   = (const float*)d_in[3];
    const float* wkv_b  = (const float*)d_in[4];
    const float* wo     = (const float*)d_in[5];
    const float* fcos   = (const float*)d_in[6];
    const float* fsin   = (const float*)d_in[7];
    if (ws_size < (size_t)WS_NEED) return;

    char* ws = (char*)d_ws;
    bfu* xb   = (bfu*)(ws + O_XB);
    bfu* wqb  = (bfu*)(ws + O_WQ);
    bfu* wab  = (bfu*)(ws + O_WA);
    bfu* wkb  = (bfu*)(ws + O_WKB);
    bfu* wvb  = (bfu*)(ws + O_WVB);
    bfu* wob  = (bfu*)(ws + O_WO);
    bfu* kall = (bfu*)(ws + O_KALL);
    bfu* kv1  = (bfu*)(ws + O_KV1);
    bfu* qr   = (bfu*)(ws + O_QR);
    bfu* kvc  = (bfu*)(ws + O_KVC);
    bfu* kpe  = (bfu*)(ws + O_KPE);
    bfu* ao   = (bfu*)(ws + O_AO);
    bfu* vt   = xb;                   // alias (xb dead after projections)

    // 1. all casts in one dispatch
    cast_all<<<29952, 256, 0, stream>>>(x, wq, wkv_a, wkv_b, wo,
                                        xb, wqb, wab, wkb, wvb, wob);

    // 2. q-proj (256-tile pipelined) -> qr rope-layout
    gemm256<0><<<dim3(12, 32), 512, 0, stream>>>(xb, wqb, qr, 3072, DD);

    // 3. kv_a proj (128-tile) -> compact kv1 [8192][640]
    gemm_bt<0><<<dim3(5, 64), 256, 0, stream>>>(xb, wab, kv1, nullptr, 640, DD);

    // 4. rmsnorm + k_pe rope
    rms_rope_kv<<<ROWS, 256, 0, stream>>>(kv1, kvnw, kvc, kpe, fcos, fsin);

    // 5. kv_b K-part -> kall ; V^T -> vt (both 256-tile pipelined)
    gemm256<2><<<dim3(8, 32), 512, 0, stream>>>(kvc, wkb, kall, 2048, KVR);
    gemm256<4><<<dim3(32, 8), 512, 0, stream>>>(wvb, kvc, vt, 8192, KVR);

    // 6. in-place q-pe rope + kall pe fill
    rope_pe_fill<<<8192, 256, 0, stream>>>(qr, kpe, kall, fcos, fsin);

    // 7. attention
    attn<<<1024, 512, 0, stream>>>(qr, kall, vt, ao);

    // 8. output projection (256-tile pipelined, fp32 out)
    gemm256<1><<<dim3(8, 32), 512, 0, stream>>>(ao, wob, d_out, 2048, HH * VD);
}

// Round 18
// 436.383 us; speedup vs baseline: 1.1760x; 1.0679x over previous
//
#include <hip/hip_runtime.h>
#include <math.h>

// ---------------- problem constants ----------------
#define BB 4
#define SS 2048
#define DD 2048
#define HH 16
#define NOPE 128
#define ROPE 64
#define VD 128
#define QKD 192         // NOPE+ROPE
#define KVR 512
#define ROWS (BB*SS)    // 8192
// log2(e) / sqrt(192), folded into wq at cast time
#define SCL2 0.1041216338380858f

typedef __attribute__((ext_vector_type(8))) short bf16x8;
typedef __attribute__((ext_vector_type(4))) float f32x4;
typedef unsigned short bfu;
typedef __attribute__((address_space(1))) const void GV;
typedef __attribute__((address_space(3))) void LV;

__device__ __forceinline__ float bf2f(unsigned int u) {
    unsigned int i = u << 16; float f; __builtin_memcpy(&f, &i, 4); return f;
}
__device__ __forceinline__ unsigned int f2bf(float f) {
    unsigned int i; __builtin_memcpy(&i, &f, 4);
    return (i + 0x7fffu + ((i >> 16) & 1u)) >> 16;
}
__device__ __forceinline__ unsigned int cvt_pk_bf16(float lo, float hi) {
    unsigned int r;
    asm("v_cvt_pk_bf16_f32 %0, %1, %2" : "=v"(r) : "v"(lo), "v"(hi));
    return r;
}

// ---------------- one fused cast: x | wq*SCL2 | wkv_a(+pad) | wkv_b(->wkb/wvb) | wo ----------------
__global__ void cast_all(const float* __restrict__ x, const float* __restrict__ wq,
                         const float* __restrict__ wa, const float* __restrict__ wb,
                         const float* __restrict__ wo,
                         bfu* __restrict__ dx, bfu* __restrict__ dq,
                         bfu* __restrict__ da, bfu* __restrict__ dkb,
                         bfu* __restrict__ dvb, bfu* __restrict__ dwo) {
    long i = (long)blockIdx.x * 256 + threadIdx.x;   // one float4 each
    const float* src; bfu* dst; long off, n_src; float scl = 1.0f;
    if (i < 4194304L)        { src = x;  dst = dx;  off = i;            n_src = 4194304L; }
    else if (i < 5767168L)   { src = wq; dst = dq;  off = i - 4194304L; n_src = 1572864L; scl = SCL2; }
    else if (i < 6094848L)   { src = wa; dst = da;  off = i - 5767168L; n_src = 294912L;  }
    else if (i < 6619136L)   {          // wkv_b: split K-rows / V-rows
        long off2 = i - 6094848L;       // float4 index into wkv_b [4096][128]
        long row = off2 >> 7, c = off2 & 127;
        long h = row >> 8, wi = row & 255;
        bfu* d2 = (wi < 128) ? dkb : dvb;
        long drow = (h << 7) + (wi & 127);
        float4 v = ((const float4*)wb)[off2];
        unsigned int lo = f2bf(v.x) | (f2bf(v.y) << 16);
        unsigned int hi = f2bf(v.z) | (f2bf(v.w) << 16);
        ((uint2*)d2)[drow * 128 + c] = make_uint2(lo, hi);
        return;
    }
    else if (i < 7667712L)   { src = wo; dst = dwo; off = i - 6619136L; n_src = 1048576L; }
    else return;
    unsigned int lo = 0, hi = 0;
    if (off < n_src) {
        float4 v = ((const float4*)src)[off];
        lo = f2bf(v.x * scl) | (f2bf(v.y * scl) << 16);
        hi = f2bf(v.z * scl) | (f2bf(v.w * scl) << 16);
    }
    ((uint2*)dst)[off] = make_uint2(lo, hi);
}

// ---------------- 256x256 tile bf16 GEMM, 8 waves, 4-phase dbuf pipeline ----------------
// MODE 0 (merged proj1, logical N=3840): col<3072 -> qr rope-layout; col<3712 -> kv1; else skip.
// MODE 1: f32 linear out.
// MODE 2 (kv_b K-part, N=2048): col=h*128+d -> kall.
// MODE 4 (V^T, M=2048, N=8192): row=h*128+v, col=b*2048+s -> vt[b][h][v][s].
template <int MODE>
__global__ void __launch_bounds__(512)
gemm256(const bfu* __restrict__ A, const bfu* __restrict__ Bt,
        void* __restrict__ Cv, bfu* __restrict__ C2, int N, int K) {
    __shared__ __align__(16) char lds[131072];
    const int tid  = threadIdx.x;
    const int lane = tid & 63;
    const int wid  = tid >> 6;
    const int wm   = wid >> 2, wn = wid & 3;
    const int nwg  = gridDim.x * gridDim.y;
    const int flat = blockIdx.y * gridDim.x + blockIdx.x;
    const int swz  = (flat & 7) * (nwg >> 3) + (flat >> 3);
    const long m0 = (long)(swz / gridDim.x) * 256;
    const long n0 = (long)(swz % gridDim.x) * 256;

    // ---- staging descriptors: per half-tile, thread covers 2x16B chunks ----
    int rowj[2], ssj[2], dstj[2];
#pragma unroll
    for (int j = 0; j < 2; ++j) {
        int idx = j * 512 + tid;
        rowj[j] = idx >> 3;              // 0..127 within half
        ssj[j]  = (idx & 7) ^ (rowj[j] & 7);
        dstj[j] = idx * 16;
    }
    const long Kl = K;
    const bfu* aS[2]; const bfu* bS[2];
#pragma unroll
    for (int j = 0; j < 2; ++j) {
        aS[j] = A  + (m0 + rowj[j]) * Kl + ssj[j] * 8;
        bS[j] = Bt + (n0 + rowj[j]) * Kl + ssj[j] * 8;
    }
    const long hstep = 128 * Kl;         // advance to half-1 rows

    f32x4 acc[8][4] = {};
    const int NT = K >> 6;

    // ---- prologue: full K-tile 0 -> buf 0 ----
#pragma unroll
    for (int h = 0; h < 2; ++h)
#pragma unroll
        for (int j = 0; j < 2; ++j) {
            __builtin_amdgcn_global_load_lds((GV*)(aS[j] + h * hstep),
                (LV*)(lds + h * 16384 + dstj[j]), 16, 0, 0);
            __builtin_amdgcn_global_load_lds((GV*)(bS[j] + h * hstep),
                (LV*)(lds + 65536 + h * 16384 + dstj[j]), 16, 0, 0);
        }
    asm volatile("s_waitcnt vmcnt(0)" ::: "memory");
    __builtin_amdgcn_s_barrier();

    // ---- read-base offsets: XOR key reduces to lane&7 (frag rows = 0 mod 16) ----
    const int k0s = (lane >> 4) ^ (lane & 7);
    const int k1s = k0s ^ 4;
    const int aro = wm * 16384 + (lane & 15) * 128;
    const int bro = (wn >> 1) * 16384 + ((wn & 1) * 64 + (lane & 15)) * 128;

    for (int kt = 0; kt < NT; ++kt) {
        const int cur = kt & 1;
        const char* Ab = lds + cur * 32768;
        const char* Bb = lds + 65536 + cur * 32768;
        char* An = lds + (cur ^ 1) * 32768;
        char* Bn = lds + 65536 + (cur ^ 1) * 32768;
        const long knext = (long)(kt + 1) << 6;
        const bool more = (kt + 1) < NT;

        const char* a0 = Ab + aro + k0s * 16;
        const char* a1 = Ab + aro + k1s * 16;
        const char* b0 = Bb + bro + k0s * 16;
        const char* b1 = Bb + bro + k1s * 16;

        bf16x8 av[4][2], bv[4][2];

        // phase 0: stage A-half0(kt+1); read av(m0-3)+bv(n0-1); mfma q00
        if (more) {
#pragma unroll
            for (int j = 0; j < 2; ++j)
                __builtin_amdgcn_global_load_lds((GV*)(aS[j] + knext), (LV*)(An + dstj[j]), 16, 0, 0);
        }
#pragma unroll
        for (int mi = 0; mi < 4; ++mi) {
            av[mi][0] = *(const bf16x8*)(a0 + mi * 2048);
            av[mi][1] = *(const bf16x8*)(a1 + mi * 2048);
        }
#pragma unroll
        for (int ni = 0; ni < 2; ++ni) {
            bv[ni][0] = *(const bf16x8*)(b0 + ni * 2048);
            bv[ni][1] = *(const bf16x8*)(b1 + ni * 2048);
        }
#pragma unroll
        for (int mi = 0; mi < 4; ++mi)
#pragma unroll
            for (int ni = 0; ni < 2; ++ni)
#pragma unroll
                for (int kk = 0; kk < 2; ++kk)
                    acc[mi][ni] = __builtin_amdgcn_mfma_f32_16x16x32_bf16(av[mi][kk], bv[ni][kk], acc[mi][ni], 0, 0, 0);

        // phase 1: stage A-half1; read bv(n2-3); mfma q01
        if (more) {
#pragma unroll
            for (int j = 0; j < 2; ++j)
                __builtin_amdgcn_global_load_lds((GV*)(aS[j] + hstep + knext), (LV*)(An + 16384 + dstj[j]), 16, 0, 0);
        }
#pragma unroll
        for (int ni = 0; ni < 2; ++ni) {
            bv[2 + ni][0] = *(const bf16x8*)(b0 + (2 + ni) * 2048);
            bv[2 + ni][1] = *(const bf16x8*)(b1 + (2 + ni) * 2048);
        }
#pragma unroll
        for (int mi = 0; mi < 4; ++mi)
#pragma unroll
            for (int ni = 0; ni < 2; ++ni)
#pragma unroll
                for (int kk = 0; kk < 2; ++kk)
                    acc[mi][2 + ni] = __builtin_amdgcn_mfma_f32_16x16x32_bf16(av[mi][kk], bv[2 + ni][kk], acc[mi][2 + ni], 0, 0, 0);

        // phase 2: stage B-half0; read av(m4-7); mfma q10
        if (more) {
#pragma unroll
            for (int j = 0; j < 2; ++j)
                __builtin_amdgcn_global_load_lds((GV*)(bS[j] + knext), (LV*)(Bn + dstj[j]), 16, 0, 0);
        }
#pragma unroll
        for (int mi = 0; mi < 4; ++mi) {
            av[mi][0] = *(const bf16x8*)(a0 + (4 + mi) * 2048);
            av[mi][1] = *(const bf16x8*)(a1 + (4 + mi) * 2048);
        }
#pragma unroll
        for (int mi = 0; mi < 4; ++mi)
#pragma unroll
            for (int ni = 0; ni < 2; ++ni)
#pragma unroll
                for (int kk = 0; kk < 2; ++kk)
                    acc[4 + mi][ni] = __builtin_amdgcn_mfma_f32_16x16x32_bf16(av[mi][kk], bv[ni][kk], acc[4 + mi][ni], 0, 0, 0);

        // phase 3: stage B-half1; mfma q11
        if (more) {
#pragma unroll
            for (int j = 0; j < 2; ++j)
                __builtin_amdgcn_global_load_lds((GV*)(bS[j] + hstep + knext), (LV*)(Bn + 16384 + dstj[j]), 16, 0, 0);
        }
#pragma unroll
        for (int mi = 0; mi < 4; ++mi)
#pragma unroll
            for (int ni = 0; ni < 2; ++ni)
#pragma unroll
                for (int kk = 0; kk < 2; ++kk)
                    acc[4 + mi][2 + ni] = __builtin_amdgcn_mfma_f32_16x16x32_bf16(av[mi][kk], bv[2 + ni][kk], acc[4 + mi][2 + ni], 0, 0, 0);

        if (more) {
            asm volatile("s_waitcnt vmcnt(0)" ::: "memory");   // own kt+1 loads landed
            __builtin_amdgcn_s_barrier();                      // all waves: tile ready + done reading cur
        }
    }

    // ---- epilogue ----
    const int cr = (lane >> 4) << 2;
    const int cc = lane & 15;
#pragma unroll
    for (int m = 0; m < 8; ++m)
#pragma unroll
        for (int n = 0; n < 4; ++n)
#pragma unroll
            for (int r = 0; r < 4; ++r) {
                long row = m0 + wm * 128 + m * 16 + cr + r;
                long col = n0 + wn * 64 + n * 16 + cc;
                float val = acc[m][n][r];
                if (MODE == 1) {
                    ((float*)Cv)[row * N + col] = val;
                } else if (MODE == 0) {   // merged proj1: qr | kv1 | skip
                    long b_ = row >> 11;
                    long s  = row & 2047;
                    if (col < 3072) {
                        unsigned int h = (unsigned int)col / 192u;
                        unsigned int d = (unsigned int)col - h * 192u;
                        ((bfu*)Cv)[((b_ * HH + h) * SS + s) * (long)QKD + d] = (bfu)f2bf(val);
                    } else if (col < 3712) {
                        C2[row * 640 + (col - 3072)] = (bfu)f2bf(val);
                    }
                } else if (MODE == 2) {   // kv_b K-part -> kall
                    long b_ = row >> 11;
                    long s  = row & 2047;
                    long h  = col >> 7;
                    long d  = col & 127;
                    ((bfu*)Cv)[((b_ * HH + h) * SS + s) * (long)QKD + d] = (bfu)f2bf(val);
                } else {                  // MODE 4: V^T -> vt[b][h][v][s]
                    long h  = row >> 7;
                    long v  = row & 127;
                    long b_ = col >> 11;
                    long s  = col & 2047;
                    ((bfu*)Cv)[(((b_ * HH + h) * VD) + v) * SS + s] = (bfu)f2bf(val);
                }
            }
}

// ---------------- merged: in-place RoPE on qr pe-cols + kall pe fill ----------------
__global__ void rope_pe_fill(bfu* __restrict__ qr, const bfu* __restrict__ kpe,
                             bfu* __restrict__ kall,
                             const float* __restrict__ fc, const float* __restrict__ fs) {
    long t = (long)blockIdx.x * 256 + threadIdx.x;
    int  ch = (int)(t & 7);
    long r  = t >> 3;
    int  s  = (int)(r & 2047);
    long bh = (r >> 11) & 63;
    long b_ = bh >> 4;
    if (t < 1048576L) {
        bfu* p = qr + (bh * SS + s) * (long)QKD + NOPE + ch * 8;
        bf16x8 v = *(const bf16x8*)p;
        int i0 = ch * 4;
        unsigned int out[4];
#pragma unroll
        for (int k = 0; k < 4; ++k) {
            float e = bf2f((unsigned short)v[2 * k]);
            float o = bf2f((unsigned short)v[2 * k + 1]);
            float c = fc[s * 32 + i0 + k], sn = fs[s * 32 + i0 + k];
            out[k] = cvt_pk_bf16(e * c - o * sn, e * sn + o * c);
        }
        *(uint4*)p = make_uint4(out[0], out[1], out[2], out[3]);
    } else {
        bf16x8 v = *(const bf16x8*)(kpe + (b_ * SS + s) * (long)ROPE + ch * 8);
        *(bf16x8*)(kall + (bh * SS + s) * (long)QKD + NOPE + ch * 8) = v;
    }
}

// ---------------- RMSNorm(kv_c) + RoPE(k_pe), one block per (b,s) row ----------------
__global__ void __launch_bounds__(256)
rms_rope_kv(const bfu* __restrict__ kv1, const float* __restrict__ wn,
            bfu* __restrict__ kvc, bfu* __restrict__ kpe,
            const float* __restrict__ fc, const float* __restrict__ fs) {
    const int row = blockIdx.x;            // b*S + s
    const int t   = threadIdx.x;
    const int s   = row & (SS - 1);
    const long base = (long)row * 640;
    unsigned int v = *(const unsigned int*)(kv1 + base + 2 * t);
    float a = bf2f(v & 0xffff), c2 = bf2f(v >> 16);
    float ssum = a * a + c2 * c2;
#pragma unroll
    for (int d = 1; d < 64; d <<= 1) ssum += __shfl_xor(ssum, d);
    __shared__ float red[4];
    const int lane = t & 63, w = t >> 6;
    if (lane == 0) red[w] = ssum;
    __syncthreads();
    float tot = red[0] + red[1] + red[2] + red[3];
    float scale = rsqrtf(tot * (1.0f / 512.0f) + 1e-6f);
    float w0 = wn[2 * t], w1 = wn[2 * t + 1];
    unsigned int out = f2bf(a * scale * w0) | (f2bf(c2 * scale * w1) << 16);
    *(unsigned int*)(kvc + (long)row * KVR + 2 * t) = out;
    if (t < 32) {
        unsigned int pv = *(const unsigned int*)(kv1 + base + KVR + 2 * t);
        float e = bf2f(pv & 0xffff), o = bf2f(pv >> 16);
        float cc = fc[s * 32 + t], sn = fs[s * 32 + t];
        unsigned int po = f2bf(e * cc - o * sn) | (f2bf(e * sn + o * cc) << 16);
        *(unsigned int*)(kpe + (long)row * ROPE + 2 * t) = po;
    }
}

// ---------------- flash causal attention (R13/R15 best) ----------------
template <bool MASKED>
__device__ __forceinline__ void attn_tile64(
    const char* kbuf, const char* vbuf, char* pw,
    const bf16x8 (&qf)[6], f32x4 (&accv)[8],
    float& ms, float& ls, int kv0, int qa, int ql, int kg, int lane) {
    // ---- QK^T from LDS: C[kv][q] ----
    f32x4 sc[4] = {};
#pragma unroll
    for (int j = 0; j < 4; ++j)
#pragma unroll
        for (int d = 0; d < 6; ++d) {
            int row  = j * 16 + ql;
            int slot = (d * 4 + kg) ^ (ql & 7);
            bf16x8 kf = *(const bf16x8*)(kbuf + row * 384 + slot * 16);
            sc[j] = __builtin_amdgcn_mfma_f32_16x16x32_bf16(kf, qf[d], sc[j], 0, 0, 0);
        }
    // ---- online softmax ----
    float p[4][4];
    float mx = -1e30f;
#pragma unroll
    for (int j = 0; j < 4; ++j)
#pragma unroll
        for (int r = 0; r < 4; ++r) {
            float s = sc[j][r];
            if (MASKED) {
                int kv = kv0 + j * 16 + kg * 4 + r;
                s = (kv > qa) ? -1e30f : s;
            }
            p[j][r] = s;
            mx = fmaxf(mx, s);
        }
    mx = fmaxf(mx, __shfl_xor(mx, 16));
    mx = fmaxf(mx, __shfl_xor(mx, 32));
    float rs = 0.f;
    if (__all(mx <= ms)) {            // defer-max
#pragma unroll
        for (int j = 0; j < 4; ++j)
#pragma unroll
            for (int r = 0; r < 4; ++r) {
                float e = exp2f(p[j][r] - ms);
                p[j][r] = e;
                rs += e;
            }
        rs += __shfl_xor(rs, 16);
        rs += __shfl_xor(rs, 32);
        ls += rs;
    } else {
        float mn = fmaxf(ms, mx);
        float al = exp2f(ms - mn);
        ms = mn;
#pragma unroll
        for (int j = 0; j < 4; ++j)
#pragma unroll
            for (int r = 0; r < 4; ++r) {
                float e = exp2f(p[j][r] - mn);
                p[j][r] = e;
                rs += e;
            }
        rs += __shfl_xor(rs, 16);
        rs += __shfl_xor(rs, 32);
        ls = ls * al + rs;
        float alT[4];
#pragma unroll
        for (int r = 0; r < 4; ++r)
            alT[r] = __shfl(al, (lane & 48) + kg * 4 + r);
#pragma unroll
        for (int v8 = 0; v8 < 8; ++v8)
#pragma unroll
            for (int r = 0; r < 4; ++r)
                accv[v8][r] *= alT[r];
    }
    // ---- repack P -> wave LDS, cvt_pk ----
#pragma unroll
    for (int j = 0; j < 4; ++j) {
        uint2 u;
        u.x = cvt_pk_bf16(p[j][0], p[j][1]);
        u.y = cvt_pk_bf16(p[j][2], p[j][3]);
        int slot = (2 * j + (kg >> 1)) ^ (ql & 7);
        *(uint2*)(pw + ql * 128 + slot * 16 + (kg & 1) * 8) = u;
    }
    asm volatile("s_waitcnt lgkmcnt(0)" ::: "memory");
    // ---- PV from LDS ----
#pragma unroll
    for (int t2 = 0; t2 < 2; ++t2) {
        int ps = (t2 * 4 + kg) ^ (ql & 7);
        bf16x8 pa = *(const bf16x8*)(pw + ql * 128 + ps * 16);
#pragma unroll
        for (int v8 = 0; v8 < 8; ++v8) {
            int vrow = v8 * 16 + ql;
            int vs   = (t2 * 4 + kg) ^ (ql & 7);
            bf16x8 vf = *(const bf16x8*)(vbuf + vrow * 128 + vs * 16);
            accv[v8] = __builtin_amdgcn_mfma_f32_16x16x32_bf16(pa, vf, accv[v8], 0, 0, 0);
        }
    }
}

__global__ void __launch_bounds__(512)
attn(const bfu* __restrict__ qr, const bfu* __restrict__ kall,
     const bfu* __restrict__ vt, bfu* __restrict__ ao) {
    __shared__ __align__(16) char kbuf[2][64 * 384];   // 2 x 24576
    __shared__ __align__(16) char vbuf[2][128 * 128];  // 2 x 16384
    __shared__ __align__(16) char pbuf[8][2048];       // 16384 -> 98304 total
    const int tid  = threadIdx.x;
    const int lane = tid & 63;
    const int w    = tid >> 6;           // 0..7
    const int ql   = lane & 15;
    const int kg   = lane >> 4;
    const int bid  = blockIdx.x;
    const int qb   = 15 - (bid >> 6);    // longest blocks first
    const int bh   = bid & 63;
    const int h    = bh & 15;
    const int b    = bh >> 4;
    const char* Q  = (const char*)(qr + (long)bh * SS * QKD);
    const char* Kp = (const char*)(kall + (long)bh * SS * QKD);
    const char* Vp = (const char*)(vt + (long)bh * VD * SS);
    char* pw = pbuf[w];

    const int qa_min = qb * 128 + w * 16;
    const int qa = qa_min + ql;

    const char* ksrc[3]; int kdst[3];
#pragma unroll
    for (int i = 0; i < 3; ++i) {
        int idx  = i * 512 + tid;
        int row  = idx / 24;
        int slot = idx - row * 24;
        int ss   = slot ^ (row & 7);
        ksrc[i]  = Kp + (long)row * 384 + ss * 16;
        kdst[i]  = idx * 16;
    }
    const char* vsrc[2]; int vdst[2];
#pragma unroll
    for (int i = 0; i < 2; ++i) {
        int idx  = i * 512 + tid;
        int row  = idx >> 3;
        int slot = idx & 7;
        int ss   = slot ^ (row & 7);
        vsrc[i]  = Vp + (long)row * (SS * 2) + ss * 16;
        vdst[i]  = idx * 16;
    }
    auto stage = [&](int bi, int kv0) {
        const long ko = (long)kv0 * 384;
        const long vo = (long)kv0 * 2;
#pragma unroll
        for (int i = 0; i < 3; ++i)
            __builtin_amdgcn_global_load_lds((GV*)(ksrc[i] + ko), (LV*)(kbuf[bi] + kdst[i]), 16, 0, 0);
#pragma unroll
        for (int i = 0; i < 2; ++i)
            __builtin_amdgcn_global_load_lds((GV*)(vsrc[i] + vo), (LV*)(vbuf[bi] + vdst[i]), 16, 0, 0);
    };

    bf16x8 qf[6];
#pragma unroll
    for (int d = 0; d < 6; ++d)
        qf[d] = *(const bf16x8*)(Q + (long)(qa_min + ql) * 384 + d * 64 + kg * 16);

    f32x4 accv[8] = {};
    float ms = -1e30f, ls = 0.f;
    const int ntiles = 2 * qb + 2;

    stage(0, 0);                         // prologue prefetch
    __syncthreads();                     // drains vmcnt(0): buf0 ready

    for (int t = 0; t < ntiles; ++t) {
        const int cur = t & 1;
        const int kv0 = t * 64;
        if (t + 1 < ntiles)
            stage(cur ^ 1, kv0 + 64);    // issue next tile; latency hides under compute
        if (kv0 + 63 <= qa_min)
            attn_tile64<false>(kbuf[cur], vbuf[cur], pw, qf, accv, ms, ls, kv0, qa, ql, kg, lane);
        else if (kv0 <= qa_min + 15)
            attn_tile64<true>(kbuf[cur], vbuf[cur], pw, qf, accv, ms, ls, kv0, qa, ql, kg, lane);
        asm volatile("s_waitcnt vmcnt(0)" ::: "memory");
        __builtin_amdgcn_s_barrier();
        asm volatile("" ::: "memory");
    }
    float li[4];
#pragma unroll
    for (int r = 0; r < 4; ++r)
        li[r] = 1.0f / __shfl(ls, (lane & 48) + kg * 4 + r);
#pragma unroll
    for (int v8 = 0; v8 < 8; ++v8)
#pragma unroll
        for (int r = 0; r < 4; ++r) {
            float o = accv[v8][r] * li[r];
            long row = (long)b * SS + qa_min + kg * 4 + r;
            ao[row * (long)(HH * VD) + h * VD + v8 * 16 + ql] = (bfu)f2bf(o);
        }
}

// ---------------- workspace layout (bytes) ----------------
#define O_XB   0L                     // x bf16 33,554,432      (later: vt alias)
#define O_WQ   33554432L              // wq bf16 12,582,912 (scaled by SCL2)
#define O_WA   46137344L              // wkv_a padded 2,621,440 (contiguous after wq)
#define O_WKB  48758784L              // wkv_b K-part [2048][512] 2,097,152
#define O_WVB  50855936L              // wkv_b V-part [2048][512] 2,097,152
#define O_WO   52953088L              // wo 8,388,608
#define O_KALL 61341696L              // K assembled 50,331,648
#define O_KV1  111673344L             // kv_a compact out 8192x640 bf16 = 10,485,760
#define O_QR   122159104L             // q rope-layout 50,331,648 (written by proj1)
#define O_KVC  172490752L             // kv_c 8,388,608
#define O_KPE  180879360L             // k_pe 1,048,576
#define O_AO   181927936L             // attn out 33,554,432
#define WS_NEED 215482368L
// Note: merged proj1 B reads rows 3712..3839 (beyond wab) land in wkb/wvb
// regions — in-workspace garbage, computed then discarded (epilogue guard).

extern "C" void kernel_launch(void* const* d_in, const int* in_sizes, int n_in,
                              void* d_out, int out_size, void* d_ws, size_t ws_size,
                              hipStream_t stream) {
    const float* x      = (const float*)d_in[0];
    const float* wq     = (const float*)d_in[1];
    const float* wkv_a  = (const float*)d_in[2];
    const float* kvnw   = (const float*)d_in[3];
    const float* wkv_b  = (const float*)d_in[4];
    const float* wo     = (const float*)d_in[5];
    const float* fcos   = (const float*)d_in[6];
    const float* fsin   = (const float*)d_in[7];
    if (ws_size < (size_t)WS_NEED) return;

    char* ws = (char*)d_ws;
    bfu* xb   = (bfu*)(ws + O_XB);
    bfu* wqb  = (bfu*)(ws + O_WQ);
    bfu* wab  = (bfu*)(ws + O_WA);
    bfu* wkb  = (bfu*)(ws + O_WKB);
    bfu* wvb  = (bfu*)(ws + O_WVB);
    bfu* wob  = (bfu*)(ws + O_WO);
    bfu* kall = (bfu*)(ws + O_KALL);
    bfu* kv1  = (bfu*)(ws + O_KV1);
    bfu* qr   = (bfu*)(ws + O_QR);
    bfu* kvc  = (bfu*)(ws + O_KVC);
    bfu* kpe  = (bfu*)(ws + O_KPE);
    bfu* ao   = (bfu*)(ws + O_AO);
    bfu* vt   = xb;                   // alias (xb dead after proj1 GEMM)

    // 1. all casts in one dispatch
    cast_all<<<29952, 256, 0, stream>>>(x, wq, wkv_a, wkv_b, wo,
                                        xb, wqb, wab, wkb, wvb, wob);

    // 2. merged proj1 (256-tile pipelined, logical N=3840 = q 3072 | kv_a 640 | pad 128)
    gemm256<0><<<dim3(15, 32), 512, 0, stream>>>(xb, wqb, qr, kv1, 3840, DD);

    // 3. rmsnorm + k_pe rope (reads compact kv1)
    rms_rope_kv<<<ROWS, 256, 0, stream>>>(kv1, kvnw, kvc, kpe, fcos, fsin);

    // 4. kv_b K-part -> kall ; V^T -> vt (both 256-tile pipelined)
    gemm256<2><<<dim3(8, 32), 512, 0, stream>>>(kvc, wkb, kall, nullptr, 2048, KVR);
    gemm256<4><<<dim3(32, 8), 512, 0, stream>>>(wvb, kvc, vt, nullptr, 8192, KVR);

    // 5. in-place q-pe rope + kall pe fill
    rope_pe_fill<<<8192, 256, 0, stream>>>(qr, kpe, kall, fcos, fsin);

    // 6. attention
    attn<<<1024, 512, 0, stream>>>(qr, kall, vt, ao);

    // 7. output projection (256-tile pipelined, fp32 out)
    gemm256<1><<<dim3(8, 32), 512, 0, stream>>>(ao, wob, d_out, nullptr, 2048, HH * VD);
}